// Round 13
// baseline (746.475 us; speedup 1.0000x reference)
//
#include <hip/hip_runtime.h>
#include <hip/hip_bf16.h>

// ---------------------------------------------------------------------------
// AgentAwareAttention (MI355X / gfx950) — Round 13: R8 geometry (128 rows,
// 8 compute waves) + R12 producer/consumer stores (4 dedicated store waves,
// never vmcnt-waiting). vmcnt retires IN ORDER, so compute waves (whose only
// VMEM is staging loads) never wait on stores; store waves stream with the
// write path continuously pressurized. 512 blocks x 768 thr, 78.7KB LDS,
// 2 blocks/CU, XCD-local bh.
// ---------------------------------------------------------------------------

#define N_TOK   2009
#define NPAD    2048
#define NTILES  16           // 128-col storage tiles
#define NT2     32           // 64-col compute steps in attn_pv
#define BATCH_  4
#define HEADS_  8
#define MROWS   8036
#define SCALE_  0.125f
#define RPB_A   256          // rows per rowsum block
#define RPV     128          // rows per attn_pv block
#define PFP     68           // Pf32 pitch (f32)

typedef __attribute__((ext_vector_type(8)))  short sh8;     // 8 bf16
typedef __attribute__((ext_vector_type(16))) float f32x16;  // mfma 32x32 acc

static inline int cdiv(int a, int b) { return (a + b - 1) / b; }

__device__ __forceinline__ float4 ld4(const float* p) {
    return *reinterpret_cast<const float4*>(p);
}
__device__ __forceinline__ unsigned short f2bf(float f) {
    __hip_bfloat16 h = __float2bfloat16(f);
    return *reinterpret_cast<unsigned short*>(&h);
}
__device__ __forceinline__ float bf2f(unsigned short u) {
    return __uint_as_float(((unsigned)u) << 16);
}
__device__ __forceinline__ void cvt8(const float4& a, const float4& b, sh8& hi, sh8& lo) {
    float f[8] = {a.x, a.y, a.z, a.w, b.x, b.y, b.z, b.w};
#pragma unroll
    for (int i = 0; i < 8; ++i) {
        unsigned short h = f2bf(f[i]);
        hi[i] = (short)h;
        lo[i] = (short)f2bf(f[i] - bf2f(h));
    }
}
__device__ __forceinline__ void cvt8p(const float4& a, const float4& b, sh8& hi) {
#pragma unroll
    for (int i = 0; i < 4; ++i) {
        hi[i]     = (short)f2bf((&a.x)[i]);
        hi[4 + i] = (short)f2bf((&b.x)[i]);
    }
}
typedef const __attribute__((address_space(1))) void gas_void;
typedef __attribute__((address_space(3))) void las_void;
__device__ __forceinline__ void gll16(const void* g, void* l) {
    __builtin_amdgcn_global_load_lds((gas_void*)g, (las_void*)l, 16, 0, 0);
}

__device__ __forceinline__ void bar_lgkm() {
    asm volatile("s_waitcnt lgkmcnt(0)" ::: "memory");
    __builtin_amdgcn_sched_barrier(0);
    __builtin_amdgcn_s_barrier();
    __builtin_amdgcn_sched_barrier(0);
}
__device__ __forceinline__ void bar_vm_lgkm() {
    asm volatile("s_waitcnt vmcnt(0) lgkmcnt(0)" ::: "memory");
    __builtin_amdgcn_sched_barrier(0);
    __builtin_amdgcn_s_barrier();
    __builtin_amdgcn_sched_barrier(0);
}

// ---------------------------------------------------------------------------
// convert_x: x [4,2009,512] f32 -> xh/xl frag-major [mt 64][kc 64][row 128]x8
// ---------------------------------------------------------------------------
__global__ __launch_bounds__(256)
void convert_x(const float* __restrict__ x, unsigned short* __restrict__ xh,
               unsigned short* __restrict__ xl)
{
    const int mt = blockIdx.x;           // 0..63
    const int yq = blockIdx.y;           // 0..3
    const int w  = threadIdx.x >> 6;     // 0..3
    const int kc = threadIdx.x & 63;     // k/8
    for (int it = 0; it < 2; ++it) {
        int rg = (yq * 2 + it) * 4 + w;  // rowgroup 0..31
        sh8 hi[4], lo[4];
#pragma unroll
        for (int rr = 0; rr < 4; ++rr) {
            int row = rg * 4 + rr;
            int gm = mt * 128 + row;
            int b = gm >> 11, gr = gm & 2047;
            float4 a = make_float4(0.f, 0.f, 0.f, 0.f), c = a;
            if (gr < N_TOK) {
                const float* p = x + ((size_t)b * N_TOK + gr) * 512 + kc * 8;
                a = ld4(p); c = ld4(p + 4);
            }
            cvt8(a, c, hi[rr], lo[rr]);
        }
        size_t base = ((size_t)(mt * 64 + kc) * 128 + rg * 4) * 8;
#pragma unroll
        for (int rr = 0; rr < 4; ++rr) {
            *reinterpret_cast<sh8*>(xh + base + rr * 8) = hi[rr];
            *reinterpret_cast<sh8*>(xl + base + rr * 8) = lo[rr];
        }
    }
}

// ---------------------------------------------------------------------------
// convert_w: weights [512, N] -> hi/lo frag-major [nt][kc 64][col 128]x8
// ---------------------------------------------------------------------------
__global__ __launch_bounds__(256)
void convert_w(const float* __restrict__ wqkv, const float* __restrict__ wself,
               const float* __restrict__ wout,
               unsigned short* __restrict__ qh, unsigned short* __restrict__ ql,
               unsigned short* __restrict__ sh, unsigned short* __restrict__ sl,
               unsigned short* __restrict__ oh, unsigned short* __restrict__ ol)
{
    int cid = blockIdx.x * 256 + threadIdx.x;
    int nt_all = cid >> 13, rem = cid & 8191;
    int kc = rem >> 7, col = rem & 127;
    const float* src; unsigned short *dh, *dl; int Nn, ntl;
    if (nt_all < 12)      { src = wqkv;  dh = qh; dl = ql; Nn = 1536; ntl = nt_all; }
    else if (nt_all < 20) { src = wself; dh = sh; dl = sl; Nn = 1024; ntl = nt_all - 12; }
    else                  { src = wout;  dh = oh; dl = ol; Nn = 512;  ntl = nt_all - 20; }
    float f[8];
#pragma unroll
    for (int i = 0; i < 8; ++i)
        f[i] = src[(size_t)(kc * 8 + i) * Nn + ntl * 128 + col];
    sh8 hi, lo;
    cvt8(make_float4(f[0], f[1], f[2], f[3]), make_float4(f[4], f[5], f[6], f[7]), hi, lo);
    size_t off = ((size_t)(ntl * 64 + kc) * 128 + col) * 8;
    *reinterpret_cast<sh8*>(dh + off) = hi;
    *reinterpret_cast<sh8*>(dl + off) = lo;
}

// ---------------------------------------------------------------------------
// split-bf16 MFMA GEMM: C[8192pad x N] = A * B, K=512. BM=BN=128, BK=32 dbuf.
// ---------------------------------------------------------------------------
template<int MODE>
__global__ __launch_bounds__(512)
void gemm_bf16(const unsigned short* __restrict__ Ah, const unsigned short* __restrict__ Al,
               const unsigned short* __restrict__ Bh, const unsigned short* __restrict__ Bl,
               float* __restrict__ C, const float* __restrict__ bias)
{
    __shared__ __align__(16) unsigned short AhS[2][4096], AlS[2][4096],
                                            BhS[2][4096], BlS[2][4096];
    const int tid = threadIdx.x, lane = tid & 63, wid = tid >> 6;
    const int mt = blockIdx.x, ntile = blockIdx.y;
    const int wm = wid >> 2, wn = wid & 3;
    const int lj = lane & 31, g = lane >> 5;

    const unsigned short* Asrc_h = Ah + (size_t)mt * 65536;
    const unsigned short* Asrc_l = Al + (size_t)mt * 65536;
    const unsigned short* Bsrc_h = Bh + (size_t)ntile * 65536;
    const unsigned short* Bsrc_l = Bl + (size_t)ntile * 65536;

#define GSTAGE(BUF, S) do {                                                      \
    gll16(Asrc_h + (size_t)(S) * 4096 + tid * 8, (char*)AhS[BUF] + tid * 16);    \
    gll16(Asrc_l + (size_t)(S) * 4096 + tid * 8, (char*)AlS[BUF] + tid * 16);    \
    gll16(Bsrc_h + (size_t)(S) * 4096 + tid * 8, (char*)BhS[BUF] + tid * 16);    \
    gll16(Bsrc_l + (size_t)(S) * 4096 + tid * 8, (char*)BlS[BUF] + tid * 16);    \
} while (0)

    f32x16 acc[2];
#pragma unroll
    for (int i = 0; i < 16; ++i) { acc[0][i] = 0.f; acc[1][i] = 0.f; }

    GSTAGE(0, 0);
    for (int s = 0; s < 16; ++s) {
        const int buf = s & 1;
        __syncthreads();
        if (s + 1 < 16) GSTAGE(buf ^ 1, s + 1);
#pragma unroll
        for (int ks = 0; ks < 2; ++ks) {
            const int kcl = 2 * ks + g;
            sh8 bh = *reinterpret_cast<const sh8*>(BhS[buf] + (kcl * 128 + wn * 32 + lj) * 8);
            sh8 bl = *reinterpret_cast<const sh8*>(BlS[buf] + (kcl * 128 + wn * 32 + lj) * 8);
#pragma unroll
            for (int Mt = 0; Mt < 2; ++Mt) {
                sh8 ah = *reinterpret_cast<const sh8*>(AhS[buf] + (kcl * 128 + wm * 64 + Mt * 32 + lj) * 8);
                sh8 al = *reinterpret_cast<const sh8*>(AlS[buf] + (kcl * 128 + wm * 64 + Mt * 32 + lj) * 8);
                acc[Mt] = __builtin_amdgcn_mfma_f32_32x32x16_bf16(ah, bh, acc[Mt], 0, 0, 0);
                acc[Mt] = __builtin_amdgcn_mfma_f32_32x32x16_bf16(ah, bl, acc[Mt], 0, 0, 0);
                acc[Mt] = __builtin_amdgcn_mfma_f32_32x32x16_bf16(al, bh, acc[Mt], 0, 0, 0);
            }
        }
    }
#undef GSTAGE

#pragma unroll
    for (int Mt = 0; Mt < 2; ++Mt) {
#pragma unroll
        for (int reg = 0; reg < 16; ++reg) {
            int rloc = wm * 64 + Mt * 32 + (reg & 3) + 8 * (reg >> 2) + 4 * g;
            int gm = mt * 128 + rloc;
            int b = gm >> 11, gr = gm & 2047;
            if (gr < N_TOK) {
                int coln = ntile * 128 + wn * 32 + lj;
                float v = acc[Mt][reg];
                size_t idx;
                if (MODE == 1)
                    idx = ((size_t)(coln >> 9) * MROWS + (size_t)b * N_TOK + gr) * 512 + (coln & 511);
                else if (MODE == 0)
                    idx = ((size_t)b * N_TOK + gr) * 1024 + coln;
                else {
                    v += bias[coln];
                    idx = ((size_t)b * N_TOK + gr) * 512 + coln;
                }
                C[idx] = v;
            }
        }
    }
}

// ---------------------------------------------------------------------------
// selfE: per (bh, agent a): 10x10 exp(scale * qs_r . ks_j)
// ---------------------------------------------------------------------------
__global__ __launch_bounds__(256)
void selfE_k(const float* __restrict__ proj2, float* __restrict__ selfE)
{
    __shared__ float qs[10][64];
    __shared__ float ks[10][68];
    const int a = blockIdx.x;
    const int h = blockIdx.y & 7;
    const int b = blockIdx.y >> 3;
    const size_t rowbase = (size_t)b * N_TOK + a * 10;

    for (int i = threadIdx.x; i < 320; i += 256) {
        int r = i >> 4;
        int c = (i & 15) * 4;
        const float* src = proj2 + (rowbase + (r % 10)) * 1024
                         + (r < 10 ? 0 : 512) + h * 64 + c;
        float4 v = ld4(src);
        if (r < 10) *reinterpret_cast<float4*>(&qs[r][c]) = v;
        else        *reinterpret_cast<float4*>(&ks[r - 10][c]) = v;
    }
    __syncthreads();
    if (threadIdx.x < 100) {
        int r = threadIdx.x / 10, c = threadIdx.x % 10;
        float acc = 0.f;
#pragma unroll 8
        for (int d = 0; d < 64; ++d) acc += qs[r][d] * ks[c][d];
        int bh = b * HEADS_ + h;
        selfE[((size_t)bh * 2000 + a * 10 + r) * 10 + c] = __expf(acc * SCALE_);
    }
}

// ---------------------------------------------------------------------------
// convert K -> Khg/Klg (hi/lo, [bh][t128][kc 8][row 128]x8), V -> Vtg
// ([bh][t128][jc 16][d 64]x8)
// ---------------------------------------------------------------------------
__global__ __launch_bounds__(256)
void convert_kv(const float* __restrict__ Kf, const float* __restrict__ Vf,
                unsigned short* __restrict__ Khg, unsigned short* __restrict__ Klg,
                unsigned short* __restrict__ Vtg)
{
    __shared__ float vtile[128][66];
    const int t  = blockIdx.x;
    const int h  = blockIdx.y & 7;
    const int b  = blockIdx.y >> 3;
    const int bh = blockIdx.y;
    const size_t bN = (size_t)b * N_TOK;
    const size_t tbase = ((size_t)bh * NTILES + t) * 8192;
    const int tid = threadIdx.x;

    {
        int r = tid >> 1, q = tid & 1;
        int gj = t * 128 + r;
        float4 f[8];
        if (gj < N_TOK) {
            const float* kp = Kf + (bN + gj) * 512 + h * 64 + q * 32;
#pragma unroll
            for (int i = 0; i < 8; ++i) f[i] = ld4(kp + 4 * i);
        } else {
#pragma unroll
            for (int i = 0; i < 8; ++i) f[i] = make_float4(0.f, 0.f, 0.f, 0.f);
        }
#pragma unroll
        for (int cp = 0; cp < 4; ++cp) {
            sh8 hi, lo;
            cvt8(f[2 * cp], f[2 * cp + 1], hi, lo);
            int kc = q * 4 + cp;
            size_t off = tbase + ((size_t)kc * 128 + r) * 8;
            *reinterpret_cast<sh8*>(Khg + off) = hi;
            *reinterpret_cast<sh8*>(Klg + off) = lo;
        }
    }
    {
        int r = tid >> 1, q = tid & 1;
        int gj = t * 128 + r;
        const float* vp = Vf + (bN + gj) * 512 + h * 64 + q * 32;
#pragma unroll
        for (int i = 0; i < 8; ++i) {
            float4 v = (gj < N_TOK) ? ld4(vp + 4 * i) : make_float4(0.f, 0.f, 0.f, 0.f);
            *reinterpret_cast<float4*>(&vtile[r][q * 32 + 4 * i]) = v;
        }
    }
    __syncthreads();
    {
        int d = tid & 63, jg = tid >> 6;
#pragma unroll
        for (int jj = 0; jj < 4; ++jj) {
            int jc = jg * 4 + jj;
            sh8 pk;
#pragma unroll
            for (int i = 0; i < 8; ++i) pk[i] = (short)f2bf(vtile[jc * 8 + i][d]);
            *reinterpret_cast<sh8*>(Vtg + tbase + ((size_t)jc * 64 + d) * 8) = pk;
        }
    }
}

// ---------------------------------------------------------------------------
// pass A: rowsums (hi-only QK) -> rowinv. 256 rows/block, 256 blocks,
// XCD-local bh. Staging fully overlapped (dbuf).
// ---------------------------------------------------------------------------
__global__ __launch_bounds__(512, 2)
void attn_rowsum(const float* __restrict__ Qf,
                 const unsigned short* __restrict__ Khg,
                 const float* __restrict__ selfE,
                 float* __restrict__ rowinv)
{
    __shared__ __align__(16) unsigned short KhS[2][8192];
    __shared__ float selfS[RPB_A * 10];

    const int bid = blockIdx.x;
    const int xcd = bid & 7, idx = bid >> 3;
    const int bh  = xcd * 4 + (idx >> 3);
    const int bx  = idx & 7;
    const int h = bh & 7, b = bh >> 3;
    const int tid = threadIdx.x, lane = tid & 63, wid = tid >> 6;
    const int row0 = bx * RPB_A;
    const int wr = wid * 32;
    const size_t bN = (size_t)b * N_TOK;
    const int lj = lane & 31, g = lane >> 5;

    for (int i = tid; i < RPB_A * 10; i += 512) {
        int r = i / 10, c = i - r * 10;
        int gr = row0 + r;
        selfS[i] = (gr < 2000) ? selfE[((size_t)bh * 2000 + gr) * 10 + c] : 0.f;
    }

    sh8 qh[4];
    {
        int grow = row0 + wr + lj;
        bool val = grow < N_TOK;
        const float* qp = Qf + (bN + (val ? grow : 0)) * 512 + h * 64;
#pragma unroll
        for (int ks = 0; ks < 4; ++ks) {
            int kc = 2 * ks + g;
            float4 a = val ? ld4(qp + kc * 8)     : make_float4(0.f, 0.f, 0.f, 0.f);
            float4 c = val ? ld4(qp + kc * 8 + 4) : make_float4(0.f, 0.f, 0.f, 0.f);
            cvt8p(a, c, qh[ks]);
        }
    }

    const unsigned short* ktiles = Khg + (size_t)bh * NTILES * 8192;
#define RSTAGE(T) do {                                                          \
    const unsigned short* kt = ktiles + (size_t)(T) * 8192;                     \
    char* dst = (char*)KhS[(T) & 1];                                            \
    _Pragma("unroll") for (int i = 0; i < 2; ++i)                               \
        gll16(kt + i * 4096 + tid * 8, dst + i * 8192 + tid * 16); } while (0)

    RSTAGE(0);

    float rsacc[16];
#pragma unroll
    for (int i = 0; i < 16; ++i) rsacc[i] = 0.f;

    const int alo = (row0 / 10) * 10;
    const int rmax = row0 + RPB_A - 1 < 1999 ? row0 + RPB_A - 1 : 1999;
    const int ahi = (rmax / 10) * 10 + 10;

    for (int t = 0; t < NTILES; ++t) {
        __syncthreads();
        if (t + 1 < NTILES) RSTAGE(t + 1);
        const unsigned short* kb = KhS[t & 1];
        const bool dtile = (alo < t * 128 + 128) && (ahi > t * 128);
#pragma unroll
        for (int ct = 0; ct < 4; ++ct) {
            sh8 kf[4];
#pragma unroll
            for (int ks = 0; ks < 4; ++ks)
                kf[ks] = *reinterpret_cast<const sh8*>(kb + ((2 * ks + g) * 128 + 32 * ct + lj) * 8);
            f32x16 s;
#pragma unroll
            for (int i = 0; i < 16; ++i) s[i] = 0.f;
#pragma unroll
            for (int ks = 0; ks < 4; ++ks)
                s = __builtin_amdgcn_mfma_f32_32x32x16_bf16(qh[ks], kf[ks], s, 0, 0, 0);
            const int gj = t * 128 + 32 * ct + lj;
            if (gj < N_TOK) {
#pragma unroll
                for (int reg = 0; reg < 16; ++reg) {
                    int rloc = wr + (reg & 3) + 8 * (reg >> 2) + 4 * g;
                    int grow = row0 + rloc;
                    float e = __expf(s[reg] * SCALE_);
                    if (dtile && grow < 2000) {
                        int a0 = (grow / 10) * 10;
                        unsigned cc = (unsigned)(gj - a0);
                        if (cc < 10u) e = selfS[rloc * 10 + (int)cc];
                    }
                    rsacc[reg] += e;
                }
            }
        }
    }
#undef RSTAGE

#pragma unroll
    for (int reg = 0; reg < 16; ++reg) {
        float v = rsacc[reg];
        v += __shfl_xor(v, 1);  v += __shfl_xor(v, 2);
        v += __shfl_xor(v, 4);  v += __shfl_xor(v, 8);
        v += __shfl_xor(v, 16);
        rsacc[reg] = v;
    }
    if (lj == 0) {
#pragma unroll
        for (int reg = 0; reg < 16; ++reg) {
            int rloc = wr + (reg & 3) + 8 * (reg >> 2) + 4 * g;
            int grow = row0 + rloc;
            rowinv[(size_t)bh * NPAD + row0 + rloc] =
                (grow < N_TOK) ? 1.0f / rsacc[reg] : 0.f;
        }
    }
}

// ---------------------------------------------------------------------------
// pass B: producer/consumer at R8 geometry. 768 threads = 8 compute waves
// (R8's QK/PV layout; only VMEM = staging gll16) + 4 store waves (Pf->attn,
// no vmcnt waits). Pf single-buffered [128][68] f32. 512 blocks, 128 rows,
// 64-col steps, XCD-local bh. LDS 78,656B -> 2 blocks/CU (24 waves).
// ---------------------------------------------------------------------------
__global__ __launch_bounds__(768, 6)
void attn_pv(const float* __restrict__ Qf,
             const unsigned short* __restrict__ Khg,
             const unsigned short* __restrict__ Klg,
             const unsigned short* __restrict__ Vtg,
             const float* __restrict__ selfE,
             const float* __restrict__ rowinv,
             float* __restrict__ attn,
             unsigned short* __restrict__ Ohg, unsigned short* __restrict__ Olg)
{
    extern __shared__ __align__(16) char smem[];
    unsigned short* KhS = (unsigned short*)smem;        // 4096 halfs (8KB)
    unsigned short* KlS = KhS + 4096;                   // 4096 (8KB)
    unsigned short* VtS = KlS + 4096;                   // 2 x 4096 (16KB) dbuf
    float* Pf = (float*)(VtS + 8192);                   // 128*68 f32 (34,816B)
    unsigned short* selfS = (unsigned short*)(Pf + RPV * PFP);   // 1280 (2560B)
    float* rinvS = (float*)(selfS + RPV * 10);          // 128 f32 (512B)

    const int bid = blockIdx.x;
    const int xcd = bid & 7, idx = bid >> 3;            // idx 0..63
    const int bh  = xcd * 4 + (idx >> 4);               // 4 bh per XCD
    const int bx  = idx & 15;
    const int h = bh & 7, b = bh >> 3;
    const int tid = threadIdx.x, lane = tid & 63, wid = tid >> 6;  // wid 0..11
    const int row0 = bx * RPV;
    const size_t bN = (size_t)b * N_TOK;
    const size_t abase = ((size_t)bh * N_TOK + row0) * N_TOK;
    const int lj = lane & 31, g = lane >> 5;
    const bool is_compute = (wid < 8);
    const int wr = (wid & 3) * 32;                      // compute row group
    const int cw = (wid >> 2) & 1;                      // compute col half

    for (int i = tid; i < RPV * 10; i += 768) {
        int r = i / 10, c = i - r * 10;
        int gr = row0 + r;
        selfS[i] = (gr < 2000) ? f2bf(selfE[((size_t)bh * 2000 + gr) * 10 + c]) : 0;
    }
    if (tid < RPV) rinvS[tid] = rowinv[(size_t)bh * NPAD + row0 + tid];

    // Q frags hi+lo (compute waves only)
    sh8 qh[4], ql[4];
    if (is_compute) {
        int grow = row0 + wr + lj;
        bool val = grow < N_TOK;
        const float* qp = Qf + (bN + (val ? grow : 0)) * 512 + h * 64;
#pragma unroll
        for (int ks = 0; ks < 4; ++ks) {
            int kc = 2 * ks + g;
            float4 a = val ? ld4(qp + kc * 8)     : make_float4(0.f, 0.f, 0.f, 0.f);
            float4 c = val ? ld4(qp + kc * 8 + 4) : make_float4(0.f, 0.f, 0.f, 0.f);
            cvt8(a, c, qh[ks], ql[ks]);
        }
    }

    const unsigned short* khT = Khg + (size_t)bh * NTILES * 8192;
    const unsigned short* klT = Klg + (size_t)bh * NTILES * 8192;
    const unsigned short* vtT = Vtg + (size_t)bh * NTILES * 8192;

    // staging by compute threads (tid<512): 1 gll16 per array per thread.
#define STAGE_KH(T) gll16(khT + (size_t)((T) >> 1) * 8192                           \
        + ((size_t)(tid >> 6) * 128 + 64 * ((T) & 1) + (tid & 63)) * 8,             \
        (char*)KhS + tid * 16)
#define STAGE_KL(T) gll16(klT + (size_t)((T) >> 1) * 8192                           \
        + ((size_t)(tid >> 6) * 128 + 64 * ((T) & 1) + (tid & 63)) * 8,             \
        (char*)KlS + tid * 16)
#define STAGE_VT(T) gll16(vtT + (size_t)((T) >> 1) * 8192                           \
        + ((size_t)(8 * ((T) & 1) + (tid >> 6)) * 64 + (tid & 63)) * 8,             \
        (char*)(VtS + ((T) & 1) * 4096) + tid * 16)

#define QK_PHASE(T) do {                                                            \
        const bool dtile = (alo < (T) * 64 + 64) && (ahi > (T) * 64);               \
        sh8 kfh[4], kfl[4];                                                         \
        _Pragma("unroll") for (int ks = 0; ks < 4; ++ks) {                          \
            int off = ((2 * ks + g) * 64 + 32 * cw + lj) * 8;                       \
            kfh[ks] = *reinterpret_cast<const sh8*>(KhS + off);                     \
            kfl[ks] = *reinterpret_cast<const sh8*>(KlS + off);                     \
        }                                                                           \
        f32x16 s;                                                                   \
        _Pragma("unroll") for (int i = 0; i < 16; ++i) s[i] = 0.f;                  \
        _Pragma("unroll") for (int ks = 0; ks < 4; ++ks) {                          \
            s = __builtin_amdgcn_mfma_f32_32x32x16_bf16(qh[ks], kfh[ks], s, 0,0,0); \
            s = __builtin_amdgcn_mfma_f32_32x32x16_bf16(qh[ks], kfl[ks], s, 0,0,0); \
            s = __builtin_amdgcn_mfma_f32_32x32x16_bf16(ql[ks], kfh[ks], s, 0,0,0); \
        }                                                                           \
        const int cin = 32 * cw + lj;                                               \
        const int gj  = (T) * 64 + cin;                                             \
        const bool jv = gj < N_TOK;                                                 \
        _Pragma("unroll") for (int reg = 0; reg < 16; ++reg) {                      \
            int rowl = (reg & 3) + 8 * (reg >> 2) + 4 * g;                          \
            int rloc = wr + rowl;                                                   \
            int grow = row0 + rloc;                                                 \
            float e = 0.f;                                                          \
            if (jv && grow < N_TOK) e = __expf(s[reg] * SCALE_);                    \
            if (dtile && jv && grow < 2000) {                                       \
                int a0 = (grow / 10) * 10;                                          \
                unsigned cc = (unsigned)(gj - a0);                                  \
                if (cc < 10u) e = bf2f(selfS[rloc * 10 + (int)cc]);                 \
            }                                                                       \
            Pf[rloc * PFP + cin] = e * rinvS[rloc];                                 \
        }                                                                           \
    } while (0)

#define PV_PHASE(T) do {                                                            \
        const unsigned short* vtb = VtS + ((T) & 1) * 4096;                         \
        _Pragma("unroll") for (int m = 0; m < 4; ++m) {                             \
            const float* pp = &Pf[(wr + lj) * PFP + 16 * m + 8 * g];                \
            float4 a = ld4(pp), b4 = ld4(pp + 4);                                   \
            sh8 pa; cvt8p(a, b4, pa);                                               \
            sh8 vf = *reinterpret_cast<const sh8*>(                                 \
                vtb + ((2 * m + g) * 64 + 32 * cw + lj) * 8);                       \
            oacc = __builtin_amdgcn_mfma_f32_32x32x16_bf16(pa, vf, oacc, 0, 0, 0);  \
        }                                                                           \
    } while (0)

    const int alo = (row0 / 10) * 10;
    const int rmax = row0 + RPV - 1 < 1999 ? row0 + RPV - 1 : 1999;
    const int ahi = (rmax / 10) * 10 + 10;

    f32x16 oacc;
#pragma unroll
    for (int i = 0; i < 16; ++i) oacc[i] = 0.f;

    if (is_compute) {
        STAGE_KH(0); STAGE_KL(0); STAGE_VT(0);
        bar_vm_lgkm();                          // prologue
        for (int t = 0; t < NT2; ++t) {
            QK_PHASE(t);
            bar_lgkm();                          // BAR_B: Pf(t) visible
            if (t + 1 < NT2) { STAGE_KH(t + 1); STAGE_KL(t + 1); STAGE_VT(t + 1); }
            PV_PHASE(t);
            bar_vm_lgkm();                       // BAR_A: staging landed, Pf free
        }
    } else {
        const int sw = wid - 8;                  // 0..3 -> rows sw*32..+31
        bar_lgkm();                              // prologue
        for (int t = 0; t < NT2; ++t) {
            __builtin_amdgcn_s_barrier();        // BAR_B: Pf(t) ready
            __builtin_amdgcn_sched_barrier(0);
            {
                const int gj = t * 64 + lane;
                const bool colv = gj < N_TOK;
                float* ap0 = attn + abase + gj;
#pragma unroll 8
                for (int i = 0; i < 32; ++i) {
                    int r = sw * 32 + i;
                    float v = Pf[r * PFP + lane];
                    if (colv && (row0 + r) < N_TOK)
                        ap0[(size_t)r * N_TOK] = v;   // stores never waited on
                }
            }
            bar_lgkm();                          // BAR_A: Pf reads done
        }
    }
#undef STAGE_KH
#undef STAGE_KL
#undef STAGE_VT
#undef QK_PHASE
#undef PV_PHASE

    // ---- epilogue: O -> LDS -> bf16 hi/lo frags ----
    __syncthreads();                             // full drain (once)
    float* Ofull = (float*)smem;                 // [128][68] = 34,816 B
    if (is_compute) {
#pragma unroll
        for (int reg = 0; reg < 16; ++reg) {
            int rloc = wr + (reg & 3) + 8 * (reg >> 2) + 4 * g;
            Ofull[rloc * 68 + 32 * cw + lj] = oacc[reg];
        }
    }
    __syncthreads();
    for (int task = tid; task < 1024; task += 768) {
        int row = task >> 3, kq = task & 7;
        const float* op = Ofull + row * 68 + kq * 8;
        float4 a = ld4(op), c = ld4(op + 4);
        sh8 hi, lo; cvt8(a, c, hi, lo);
        int gm = b * 2048 + row0 + row;
        int mtile = gm >> 7, row128 = gm & 127;
        size_t off = ((size_t)(mtile * 64 + h * 8 + kq) * 128 + row128) * 8;
        *reinterpret_cast<sh8*>(Ohg + off) = hi;
        *reinterpret_cast<sh8*>(Olg + off) = lo;
    }
}

// ---------------------------------------------------------------------------
extern "C" void kernel_launch(void* const* d_in, const int* in_sizes, int n_in,
                              void* d_out, int out_size, void* d_ws, size_t ws_size,
                              hipStream_t stream)
{
    const float* x         = (const float*)d_in[0];
    const float* w_qkv     = (const float*)d_in[1];
    const float* w_qk_self = (const float*)d_in[2];
    const float* w_out     = (const float*)d_in[3];
    const float* b_out     = (const float*)d_in[4];

    float* out  = (float*)d_out;                       // [8036,512]
    float* attn = out + (size_t)MROWS * 512;           // [4,8,2009,2009]

    // ---- workspace layout ----
    float* Qf = (float*)d_ws;                          // 8036*512 f32
    float* Kf = Qf + (size_t)MROWS * 512;
    float* Vf = Kf + (size_t)MROWS * 512;
    float* p2 = Vf + (size_t)MROWS * 512;              // proj2 [8036*1024] f32
    unsigned short* Khg = (unsigned short*)p2;         // then Khg/Klg/Vtg (24MB)
    unsigned short* Klg = Khg + 4194304;
    unsigned short* Vtg = Klg + 4194304;
    float* proj2 = p2;
    float* after_p2 = p2 + (size_t)MROWS * 1024;
    unsigned short* xh  = (unsigned short*)after_p2;   // 8192*512 halfs
    unsigned short* xl  = xh + 4194304;
    unsigned short* Wqh = xl + 4194304;                // 512*1536
    unsigned short* Wql = Wqh + 786432;
    unsigned short* Wsh = Wql + 786432;                // 512*1024
    unsigned short* Wsl = Wsh + 524288;
    unsigned short* Woh = Wsl + 524288;                // 512*512
    unsigned short* Wol = Woh + 262144;
    float* rowinv = (float*)(Wol + 262144);            // 32*2048
    float* selfE  = rowinv + 65536;                    // 32*2000*10
    unsigned short* Ohg = (unsigned short*)Kf;         // overlay (Kf dead)
    unsigned short* Olg = Ohg + 4194304;

    const int smem_pv = 8192 + 8192 + 16384            // Kh, Kl, Vt dbuf
                      + RPV * PFP * 4                  // Pf32 (34,816)
                      + RPV * 10 * 2 + RPV * 4;        // selfS bf16 + rinv
    // = 78,656 B -> 2 blocks/CU
    hipFuncSetAttribute((const void*)attn_pv,
                        hipFuncAttributeMaxDynamicSharedMemorySize, smem_pv);

    dim3 gx(64, 4);
    convert_x<<<gx, 256, 0, stream>>>(x, xh, xl);
    convert_w<<<768, 256, 0, stream>>>(w_qkv, w_qk_self, w_out,
                                       Wqh, Wql, Wsh, Wsl, Woh, Wol);

    dim3 g1(64, 12);
    gemm_bf16<1><<<g1, 512, 0, stream>>>(xh, xl, Wqh, Wql, Qf, nullptr);

    dim3 g2(64, 8);
    gemm_bf16<0><<<g2, 512, 0, stream>>>(xh, xl, Wsh, Wsl, proj2, nullptr);

    dim3 gs(200, 32);
    selfE_k<<<gs, 256, 0, stream>>>(proj2, selfE);

    dim3 gc(NTILES, 32);
    convert_kv<<<gc, 256, 0, stream>>>(Kf, Vf, Khg, Klg, Vtg);

    attn_rowsum<<<256, 512, 0, stream>>>(Qf, Khg, selfE, rowinv);

    attn_pv<<<512, 768, smem_pv, stream>>>(Qf, Khg, Klg, Vtg, selfE, rowinv,
                                           attn, Ohg, Olg);

    dim3 g3(64, 4);
    gemm_bf16<2><<<g3, 512, 0, stream>>>(Ohg, Olg, Woh, Wol, out, b_out);
}

// Round 14
// 473.904 us; speedup vs baseline: 1.5752x; 1.5752x over previous
//
#include <hip/hip_runtime.h>
#include <hip/hip_bf16.h>

// ---------------------------------------------------------------------------
// AgentAwareAttention (MI355X / gfx950) — Round 14: R13 producer/consumer
// with the register-spill fixed: __launch_bounds__(768, 3) gives the
// compute waves a 170-VGPR budget (R13's (768,6) capped at 85 -> oacc/frag
// spills -> 0.5GB scratch traffic, invalidating the experiment).
// 512 blocks x 768 thr (8 compute + 4 store waves), 1 block/CU, 78.7KB LDS.
// Store waves never vmcnt-wait -> write path continuously pressurized.
// ---------------------------------------------------------------------------

#define N_TOK   2009
#define NPAD    2048
#define NTILES  16           // 128-col storage tiles
#define NT2     32           // 64-col compute steps in attn_pv
#define BATCH_  4
#define HEADS_  8
#define MROWS   8036
#define SCALE_  0.125f
#define RPB_A   256          // rows per rowsum block
#define RPV     128          // rows per attn_pv block
#define PFP     68           // Pf32 pitch (f32)

typedef __attribute__((ext_vector_type(8)))  short sh8;     // 8 bf16
typedef __attribute__((ext_vector_type(16))) float f32x16;  // mfma 32x32 acc

static inline int cdiv(int a, int b) { return (a + b - 1) / b; }

__device__ __forceinline__ float4 ld4(const float* p) {
    return *reinterpret_cast<const float4*>(p);
}
__device__ __forceinline__ unsigned short f2bf(float f) {
    __hip_bfloat16 h = __float2bfloat16(f);
    return *reinterpret_cast<unsigned short*>(&h);
}
__device__ __forceinline__ float bf2f(unsigned short u) {
    return __uint_as_float(((unsigned)u) << 16);
}
__device__ __forceinline__ void cvt8(const float4& a, const float4& b, sh8& hi, sh8& lo) {
    float f[8] = {a.x, a.y, a.z, a.w, b.x, b.y, b.z, b.w};
#pragma unroll
    for (int i = 0; i < 8; ++i) {
        unsigned short h = f2bf(f[i]);
        hi[i] = (short)h;
        lo[i] = (short)f2bf(f[i] - bf2f(h));
    }
}
__device__ __forceinline__ void cvt8p(const float4& a, const float4& b, sh8& hi) {
#pragma unroll
    for (int i = 0; i < 4; ++i) {
        hi[i]     = (short)f2bf((&a.x)[i]);
        hi[4 + i] = (short)f2bf((&b.x)[i]);
    }
}
typedef const __attribute__((address_space(1))) void gas_void;
typedef __attribute__((address_space(3))) void las_void;
__device__ __forceinline__ void gll16(const void* g, void* l) {
    __builtin_amdgcn_global_load_lds((gas_void*)g, (las_void*)l, 16, 0, 0);
}

__device__ __forceinline__ void bar_lgkm() {
    asm volatile("s_waitcnt lgkmcnt(0)" ::: "memory");
    __builtin_amdgcn_sched_barrier(0);
    __builtin_amdgcn_s_barrier();
    __builtin_amdgcn_sched_barrier(0);
}
__device__ __forceinline__ void bar_vm_lgkm() {
    asm volatile("s_waitcnt vmcnt(0) lgkmcnt(0)" ::: "memory");
    __builtin_amdgcn_sched_barrier(0);
    __builtin_amdgcn_s_barrier();
    __builtin_amdgcn_sched_barrier(0);
}

// ---------------------------------------------------------------------------
// convert_x: x [4,2009,512] f32 -> xh/xl frag-major [mt 64][kc 64][row 128]x8
// ---------------------------------------------------------------------------
__global__ __launch_bounds__(256)
void convert_x(const float* __restrict__ x, unsigned short* __restrict__ xh,
               unsigned short* __restrict__ xl)
{
    const int mt = blockIdx.x;           // 0..63
    const int yq = blockIdx.y;           // 0..3
    const int w  = threadIdx.x >> 6;     // 0..3
    const int kc = threadIdx.x & 63;     // k/8
    for (int it = 0; it < 2; ++it) {
        int rg = (yq * 2 + it) * 4 + w;  // rowgroup 0..31
        sh8 hi[4], lo[4];
#pragma unroll
        for (int rr = 0; rr < 4; ++rr) {
            int row = rg * 4 + rr;
            int gm = mt * 128 + row;
            int b = gm >> 11, gr = gm & 2047;
            float4 a = make_float4(0.f, 0.f, 0.f, 0.f), c = a;
            if (gr < N_TOK) {
                const float* p = x + ((size_t)b * N_TOK + gr) * 512 + kc * 8;
                a = ld4(p); c = ld4(p + 4);
            }
            cvt8(a, c, hi[rr], lo[rr]);
        }
        size_t base = ((size_t)(mt * 64 + kc) * 128 + rg * 4) * 8;
#pragma unroll
        for (int rr = 0; rr < 4; ++rr) {
            *reinterpret_cast<sh8*>(xh + base + rr * 8) = hi[rr];
            *reinterpret_cast<sh8*>(xl + base + rr * 8) = lo[rr];
        }
    }
}

// ---------------------------------------------------------------------------
// convert_w: weights [512, N] -> hi/lo frag-major [nt][kc 64][col 128]x8
// ---------------------------------------------------------------------------
__global__ __launch_bounds__(256)
void convert_w(const float* __restrict__ wqkv, const float* __restrict__ wself,
               const float* __restrict__ wout,
               unsigned short* __restrict__ qh, unsigned short* __restrict__ ql,
               unsigned short* __restrict__ sh, unsigned short* __restrict__ sl,
               unsigned short* __restrict__ oh, unsigned short* __restrict__ ol)
{
    int cid = blockIdx.x * 256 + threadIdx.x;
    int nt_all = cid >> 13, rem = cid & 8191;
    int kc = rem >> 7, col = rem & 127;
    const float* src; unsigned short *dh, *dl; int Nn, ntl;
    if (nt_all < 12)      { src = wqkv;  dh = qh; dl = ql; Nn = 1536; ntl = nt_all; }
    else if (nt_all < 20) { src = wself; dh = sh; dl = sl; Nn = 1024; ntl = nt_all - 12; }
    else                  { src = wout;  dh = oh; dl = ol; Nn = 512;  ntl = nt_all - 20; }
    float f[8];
#pragma unroll
    for (int i = 0; i < 8; ++i)
        f[i] = src[(size_t)(kc * 8 + i) * Nn + ntl * 128 + col];
    sh8 hi, lo;
    cvt8(make_float4(f[0], f[1], f[2], f[3]), make_float4(f[4], f[5], f[6], f[7]), hi, lo);
    size_t off = ((size_t)(ntl * 64 + kc) * 128 + col) * 8;
    *reinterpret_cast<sh8*>(dh + off) = hi;
    *reinterpret_cast<sh8*>(dl + off) = lo;
}

// ---------------------------------------------------------------------------
// split-bf16 MFMA GEMM: C[8192pad x N] = A * B, K=512. BM=BN=128, BK=32 dbuf.
// ---------------------------------------------------------------------------
template<int MODE>
__global__ __launch_bounds__(512)
void gemm_bf16(const unsigned short* __restrict__ Ah, const unsigned short* __restrict__ Al,
               const unsigned short* __restrict__ Bh, const unsigned short* __restrict__ Bl,
               float* __restrict__ C, const float* __restrict__ bias)
{
    __shared__ __align__(16) unsigned short AhS[2][4096], AlS[2][4096],
                                            BhS[2][4096], BlS[2][4096];
    const int tid = threadIdx.x, lane = tid & 63, wid = tid >> 6;
    const int mt = blockIdx.x, ntile = blockIdx.y;
    const int wm = wid >> 2, wn = wid & 3;
    const int lj = lane & 31, g = lane >> 5;

    const unsigned short* Asrc_h = Ah + (size_t)mt * 65536;
    const unsigned short* Asrc_l = Al + (size_t)mt * 65536;
    const unsigned short* Bsrc_h = Bh + (size_t)ntile * 65536;
    const unsigned short* Bsrc_l = Bl + (size_t)ntile * 65536;

#define GSTAGE(BUF, S) do {                                                      \
    gll16(Asrc_h + (size_t)(S) * 4096 + tid * 8, (char*)AhS[BUF] + tid * 16);    \
    gll16(Asrc_l + (size_t)(S) * 4096 + tid * 8, (char*)AlS[BUF] + tid * 16);    \
    gll16(Bsrc_h + (size_t)(S) * 4096 + tid * 8, (char*)BhS[BUF] + tid * 16);    \
    gll16(Bsrc_l + (size_t)(S) * 4096 + tid * 8, (char*)BlS[BUF] + tid * 16);    \
} while (0)

    f32x16 acc[2];
#pragma unroll
    for (int i = 0; i < 16; ++i) { acc[0][i] = 0.f; acc[1][i] = 0.f; }

    GSTAGE(0, 0);
    for (int s = 0; s < 16; ++s) {
        const int buf = s & 1;
        __syncthreads();
        if (s + 1 < 16) GSTAGE(buf ^ 1, s + 1);
#pragma unroll
        for (int ks = 0; ks < 2; ++ks) {
            const int kcl = 2 * ks + g;
            sh8 bh = *reinterpret_cast<const sh8*>(BhS[buf] + (kcl * 128 + wn * 32 + lj) * 8);
            sh8 bl = *reinterpret_cast<const sh8*>(BlS[buf] + (kcl * 128 + wn * 32 + lj) * 8);
#pragma unroll
            for (int Mt = 0; Mt < 2; ++Mt) {
                sh8 ah = *reinterpret_cast<const sh8*>(AhS[buf] + (kcl * 128 + wm * 64 + Mt * 32 + lj) * 8);
                sh8 al = *reinterpret_cast<const sh8*>(AlS[buf] + (kcl * 128 + wm * 64 + Mt * 32 + lj) * 8);
                acc[Mt] = __builtin_amdgcn_mfma_f32_32x32x16_bf16(ah, bh, acc[Mt], 0, 0, 0);
                acc[Mt] = __builtin_amdgcn_mfma_f32_32x32x16_bf16(ah, bl, acc[Mt], 0, 0, 0);
                acc[Mt] = __builtin_amdgcn_mfma_f32_32x32x16_bf16(al, bh, acc[Mt], 0, 0, 0);
            }
        }
    }
#undef GSTAGE

#pragma unroll
    for (int Mt = 0; Mt < 2; ++Mt) {
#pragma unroll
        for (int reg = 0; reg < 16; ++reg) {
            int rloc = wm * 64 + Mt * 32 + (reg & 3) + 8 * (reg >> 2) + 4 * g;
            int gm = mt * 128 + rloc;
            int b = gm >> 11, gr = gm & 2047;
            if (gr < N_TOK) {
                int coln = ntile * 128 + wn * 32 + lj;
                float v = acc[Mt][reg];
                size_t idx;
                if (MODE == 1)
                    idx = ((size_t)(coln >> 9) * MROWS + (size_t)b * N_TOK + gr) * 512 + (coln & 511);
                else if (MODE == 0)
                    idx = ((size_t)b * N_TOK + gr) * 1024 + coln;
                else {
                    v += bias[coln];
                    idx = ((size_t)b * N_TOK + gr) * 512 + coln;
                }
                C[idx] = v;
            }
        }
    }
}

// ---------------------------------------------------------------------------
// selfE: per (bh, agent a): 10x10 exp(scale * qs_r . ks_j)
// ---------------------------------------------------------------------------
__global__ __launch_bounds__(256)
void selfE_k(const float* __restrict__ proj2, float* __restrict__ selfE)
{
    __shared__ float qs[10][64];
    __shared__ float ks[10][68];
    const int a = blockIdx.x;
    const int h = blockIdx.y & 7;
    const int b = blockIdx.y >> 3;
    const size_t rowbase = (size_t)b * N_TOK + a * 10;

    for (int i = threadIdx.x; i < 320; i += 256) {
        int r = i >> 4;
        int c = (i & 15) * 4;
        const float* src = proj2 + (rowbase + (r % 10)) * 1024
                         + (r < 10 ? 0 : 512) + h * 64 + c;
        float4 v = ld4(src);
        if (r < 10) *reinterpret_cast<float4*>(&qs[r][c]) = v;
        else        *reinterpret_cast<float4*>(&ks[r - 10][c]) = v;
    }
    __syncthreads();
    if (threadIdx.x < 100) {
        int r = threadIdx.x / 10, c = threadIdx.x % 10;
        float acc = 0.f;
#pragma unroll 8
        for (int d = 0; d < 64; ++d) acc += qs[r][d] * ks[c][d];
        int bh = b * HEADS_ + h;
        selfE[((size_t)bh * 2000 + a * 10 + r) * 10 + c] = __expf(acc * SCALE_);
    }
}

// ---------------------------------------------------------------------------
// convert K -> Khg/Klg (hi/lo, [bh][t128][kc 8][row 128]x8), V -> Vtg
// ([bh][t128][jc 16][d 64]x8)
// ---------------------------------------------------------------------------
__global__ __launch_bounds__(256)
void convert_kv(const float* __restrict__ Kf, const float* __restrict__ Vf,
                unsigned short* __restrict__ Khg, unsigned short* __restrict__ Klg,
                unsigned short* __restrict__ Vtg)
{
    __shared__ float vtile[128][66];
    const int t  = blockIdx.x;
    const int h  = blockIdx.y & 7;
    const int b  = blockIdx.y >> 3;
    const int bh = blockIdx.y;
    const size_t bN = (size_t)b * N_TOK;
    const size_t tbase = ((size_t)bh * NTILES + t) * 8192;
    const int tid = threadIdx.x;

    {
        int r = tid >> 1, q = tid & 1;
        int gj = t * 128 + r;
        float4 f[8];
        if (gj < N_TOK) {
            const float* kp = Kf + (bN + gj) * 512 + h * 64 + q * 32;
#pragma unroll
            for (int i = 0; i < 8; ++i) f[i] = ld4(kp + 4 * i);
        } else {
#pragma unroll
            for (int i = 0; i < 8; ++i) f[i] = make_float4(0.f, 0.f, 0.f, 0.f);
        }
#pragma unroll
        for (int cp = 0; cp < 4; ++cp) {
            sh8 hi, lo;
            cvt8(f[2 * cp], f[2 * cp + 1], hi, lo);
            int kc = q * 4 + cp;
            size_t off = tbase + ((size_t)kc * 128 + r) * 8;
            *reinterpret_cast<sh8*>(Khg + off) = hi;
            *reinterpret_cast<sh8*>(Klg + off) = lo;
        }
    }
    {
        int r = tid >> 1, q = tid & 1;
        int gj = t * 128 + r;
        const float* vp = Vf + (bN + gj) * 512 + h * 64 + q * 32;
#pragma unroll
        for (int i = 0; i < 8; ++i) {
            float4 v = (gj < N_TOK) ? ld4(vp + 4 * i) : make_float4(0.f, 0.f, 0.f, 0.f);
            *reinterpret_cast<float4*>(&vtile[r][q * 32 + 4 * i]) = v;
        }
    }
    __syncthreads();
    {
        int d = tid & 63, jg = tid >> 6;
#pragma unroll
        for (int jj = 0; jj < 4; ++jj) {
            int jc = jg * 4 + jj;
            sh8 pk;
#pragma unroll
            for (int i = 0; i < 8; ++i) pk[i] = (short)f2bf(vtile[jc * 8 + i][d]);
            *reinterpret_cast<sh8*>(Vtg + tbase + ((size_t)jc * 64 + d) * 8) = pk;
        }
    }
}

// ---------------------------------------------------------------------------
// pass A: rowsums (hi-only QK) -> rowinv. 256 rows/block, 256 blocks,
// XCD-local bh. Staging fully overlapped (dbuf).
// ---------------------------------------------------------------------------
__global__ __launch_bounds__(512, 2)
void attn_rowsum(const float* __restrict__ Qf,
                 const unsigned short* __restrict__ Khg,
                 const float* __restrict__ selfE,
                 float* __restrict__ rowinv)
{
    __shared__ __align__(16) unsigned short KhS[2][8192];
    __shared__ float selfS[RPB_A * 10];

    const int bid = blockIdx.x;
    const int xcd = bid & 7, idx = bid >> 3;
    const int bh  = xcd * 4 + (idx >> 3);
    const int bx  = idx & 7;
    const int h = bh & 7, b = bh >> 3;
    const int tid = threadIdx.x, lane = tid & 63, wid = tid >> 6;
    const int row0 = bx * RPB_A;
    const int wr = wid * 32;
    const size_t bN = (size_t)b * N_TOK;
    const int lj = lane & 31, g = lane >> 5;

    for (int i = tid; i < RPB_A * 10; i += 512) {
        int r = i / 10, c = i - r * 10;
        int gr = row0 + r;
        selfS[i] = (gr < 2000) ? selfE[((size_t)bh * 2000 + gr) * 10 + c] : 0.f;
    }

    sh8 qh[4];
    {
        int grow = row0 + wr + lj;
        bool val = grow < N_TOK;
        const float* qp = Qf + (bN + (val ? grow : 0)) * 512 + h * 64;
#pragma unroll
        for (int ks = 0; ks < 4; ++ks) {
            int kc = 2 * ks + g;
            float4 a = val ? ld4(qp + kc * 8)     : make_float4(0.f, 0.f, 0.f, 0.f);
            float4 c = val ? ld4(qp + kc * 8 + 4) : make_float4(0.f, 0.f, 0.f, 0.f);
            cvt8p(a, c, qh[ks]);
        }
    }

    const unsigned short* ktiles = Khg + (size_t)bh * NTILES * 8192;
#define RSTAGE(T) do {                                                          \
    const unsigned short* kt = ktiles + (size_t)(T) * 8192;                     \
    char* dst = (char*)KhS[(T) & 1];                                            \
    _Pragma("unroll") for (int i = 0; i < 2; ++i)                               \
        gll16(kt + i * 4096 + tid * 8, dst + i * 8192 + tid * 16); } while (0)

    RSTAGE(0);

    float rsacc[16];
#pragma unroll
    for (int i = 0; i < 16; ++i) rsacc[i] = 0.f;

    const int alo = (row0 / 10) * 10;
    const int rmax = row0 + RPB_A - 1 < 1999 ? row0 + RPB_A - 1 : 1999;
    const int ahi = (rmax / 10) * 10 + 10;

    for (int t = 0; t < NTILES; ++t) {
        __syncthreads();
        if (t + 1 < NTILES) RSTAGE(t + 1);
        const unsigned short* kb = KhS[t & 1];
        const bool dtile = (alo < t * 128 + 128) && (ahi > t * 128);
#pragma unroll
        for (int ct = 0; ct < 4; ++ct) {
            sh8 kf[4];
#pragma unroll
            for (int ks = 0; ks < 4; ++ks)
                kf[ks] = *reinterpret_cast<const sh8*>(kb + ((2 * ks + g) * 128 + 32 * ct + lj) * 8);
            f32x16 s;
#pragma unroll
            for (int i = 0; i < 16; ++i) s[i] = 0.f;
#pragma unroll
            for (int ks = 0; ks < 4; ++ks)
                s = __builtin_amdgcn_mfma_f32_32x32x16_bf16(qh[ks], kf[ks], s, 0, 0, 0);
            const int gj = t * 128 + 32 * ct + lj;
            if (gj < N_TOK) {
#pragma unroll
                for (int reg = 0; reg < 16; ++reg) {
                    int rloc = wr + (reg & 3) + 8 * (reg >> 2) + 4 * g;
                    int grow = row0 + rloc;
                    float e = __expf(s[reg] * SCALE_);
                    if (dtile && grow < 2000) {
                        int a0 = (grow / 10) * 10;
                        unsigned cc = (unsigned)(gj - a0);
                        if (cc < 10u) e = selfS[rloc * 10 + (int)cc];
                    }
                    rsacc[reg] += e;
                }
            }
        }
    }
#undef RSTAGE

#pragma unroll
    for (int reg = 0; reg < 16; ++reg) {
        float v = rsacc[reg];
        v += __shfl_xor(v, 1);  v += __shfl_xor(v, 2);
        v += __shfl_xor(v, 4);  v += __shfl_xor(v, 8);
        v += __shfl_xor(v, 16);
        rsacc[reg] = v;
    }
    if (lj == 0) {
#pragma unroll
        for (int reg = 0; reg < 16; ++reg) {
            int rloc = wr + (reg & 3) + 8 * (reg >> 2) + 4 * g;
            int grow = row0 + rloc;
            rowinv[(size_t)bh * NPAD + row0 + rloc] =
                (grow < N_TOK) ? 1.0f / rsacc[reg] : 0.f;
        }
    }
}

// ---------------------------------------------------------------------------
// pass B: producer/consumer at R8 geometry, spill-free. 768 threads =
// 8 compute waves (only VMEM = staging gll16) + 4 store waves (Pf->attn,
// never vmcnt-waiting). Pf single-buffered [128][68] f32. 512 blocks,
// 128 rows, 64-col steps, XCD-local bh. LDS 78,656B, 1 block/CU.
// ---------------------------------------------------------------------------
__global__ __launch_bounds__(768, 3)
void attn_pv(const float* __restrict__ Qf,
             const unsigned short* __restrict__ Khg,
             const unsigned short* __restrict__ Klg,
             const unsigned short* __restrict__ Vtg,
             const float* __restrict__ selfE,
             const float* __restrict__ rowinv,
             float* __restrict__ attn,
             unsigned short* __restrict__ Ohg, unsigned short* __restrict__ Olg)
{
    extern __shared__ __align__(16) char smem[];
    unsigned short* KhS = (unsigned short*)smem;        // 4096 halfs (8KB)
    unsigned short* KlS = KhS + 4096;                   // 4096 (8KB)
    unsigned short* VtS = KlS + 4096;                   // 2 x 4096 (16KB) dbuf
    float* Pf = (float*)(VtS + 8192);                   // 128*68 f32 (34,816B)
    unsigned short* selfS = (unsigned short*)(Pf + RPV * PFP);   // 1280 (2560B)
    float* rinvS = (float*)(selfS + RPV * 10);          // 128 f32 (512B)

    const int bid = blockIdx.x;
    const int xcd = bid & 7, idx = bid >> 3;            // idx 0..63
    const int bh  = xcd * 4 + (idx >> 4);               // 4 bh per XCD
    const int bx  = idx & 15;
    const int h = bh & 7, b = bh >> 3;
    const int tid = threadIdx.x, lane = tid & 63, wid = tid >> 6;  // wid 0..11
    const int row0 = bx * RPV;
    const size_t bN = (size_t)b * N_TOK;
    const size_t abase = ((size_t)bh * N_TOK + row0) * N_TOK;
    const int lj = lane & 31, g = lane >> 5;
    const bool is_compute = (wid < 8);
    const int wr = (wid & 3) * 32;                      // compute row group
    const int cw = (wid >> 2) & 1;                      // compute col half

    for (int i = tid; i < RPV * 10; i += 768) {
        int r = i / 10, c = i - r * 10;
        int gr = row0 + r;
        selfS[i] = (gr < 2000) ? f2bf(selfE[((size_t)bh * 2000 + gr) * 10 + c]) : 0;
    }
    if (tid < RPV) rinvS[tid] = rowinv[(size_t)bh * NPAD + row0 + tid];

    // Q frags hi+lo (compute waves only)
    sh8 qh[4], ql[4];
    if (is_compute) {
        int grow = row0 + wr + lj;
        bool val = grow < N_TOK;
        const float* qp = Qf + (bN + (val ? grow : 0)) * 512 + h * 64;
#pragma unroll
        for (int ks = 0; ks < 4; ++ks) {
            int kc = 2 * ks + g;
            float4 a = val ? ld4(qp + kc * 8)     : make_float4(0.f, 0.f, 0.f, 0.f);
            float4 c = val ? ld4(qp + kc * 8 + 4) : make_float4(0.f, 0.f, 0.f, 0.f);
            cvt8(a, c, qh[ks], ql[ks]);
        }
    }

    const unsigned short* khT = Khg + (size_t)bh * NTILES * 8192;
    const unsigned short* klT = Klg + (size_t)bh * NTILES * 8192;
    const unsigned short* vtT = Vtg + (size_t)bh * NTILES * 8192;

    // staging by compute threads (tid<512): 1 gll16 per array per thread.
#define STAGE_KH(T) gll16(khT + (size_t)((T) >> 1) * 8192                           \
        + ((size_t)(tid >> 6) * 128 + 64 * ((T) & 1) + (tid & 63)) * 8,             \
        (char*)KhS + tid * 16)
#define STAGE_KL(T) gll16(klT + (size_t)((T) >> 1) * 8192                           \
        + ((size_t)(tid >> 6) * 128 + 64 * ((T) & 1) + (tid & 63)) * 8,             \
        (char*)KlS + tid * 16)
#define STAGE_VT(T) gll16(vtT + (size_t)((T) >> 1) * 8192                           \
        + ((size_t)(8 * ((T) & 1) + (tid >> 6)) * 64 + (tid & 63)) * 8,             \
        (char*)(VtS + ((T) & 1) * 4096) + tid * 16)

#define QK_PHASE(T) do {                                                            \
        const bool dtile = (alo < (T) * 64 + 64) && (ahi > (T) * 64);               \
        sh8 kfh[4], kfl[4];                                                         \
        _Pragma("unroll") for (int ks = 0; ks < 4; ++ks) {                          \
            int off = ((2 * ks + g) * 64 + 32 * cw + lj) * 8;                       \
            kfh[ks] = *reinterpret_cast<const sh8*>(KhS + off);                     \
            kfl[ks] = *reinterpret_cast<const sh8*>(KlS + off);                     \
        }                                                                           \
        f32x16 s;                                                                   \
        _Pragma("unroll") for (int i = 0; i < 16; ++i) s[i] = 0.f;                  \
        _Pragma("unroll") for (int ks = 0; ks < 4; ++ks) {                          \
            s = __builtin_amdgcn_mfma_f32_32x32x16_bf16(qh[ks], kfh[ks], s, 0,0,0); \
            s = __builtin_amdgcn_mfma_f32_32x32x16_bf16(qh[ks], kfl[ks], s, 0,0,0); \
            s = __builtin_amdgcn_mfma_f32_32x32x16_bf16(ql[ks], kfh[ks], s, 0,0,0); \
        }                                                                           \
        const int cin = 32 * cw + lj;                                               \
        const int gj  = (T) * 64 + cin;                                             \
        const bool jv = gj < N_TOK;                                                 \
        _Pragma("unroll") for (int reg = 0; reg < 16; ++reg) {                      \
            int rowl = (reg & 3) + 8 * (reg >> 2) + 4 * g;                          \
            int rloc = wr + rowl;                                                   \
            int grow = row0 + rloc;                                                 \
            float e = 0.f;                                                          \
            if (jv && grow < N_TOK) e = __expf(s[reg] * SCALE_);                    \
            if (dtile && jv && grow < 2000) {                                       \
                int a0 = (grow / 10) * 10;                                          \
                unsigned cc = (unsigned)(gj - a0);                                  \
                if (cc < 10u) e = bf2f(selfS[rloc * 10 + (int)cc]);                 \
            }                                                                       \
            Pf[rloc * PFP + cin] = e * rinvS[rloc];                                 \
        }                                                                           \
    } while (0)

#define PV_PHASE(T) do {                                                            \
        const unsigned short* vtb = VtS + ((T) & 1) * 4096;                         \
        _Pragma("unroll") for (int m = 0; m < 4; ++m) {                             \
            const float* pp = &Pf[(wr + lj) * PFP + 16 * m + 8 * g];                \
            float4 a = ld4(pp), b4 = ld4(pp + 4);                                   \
            sh8 pa; cvt8p(a, b4, pa);                                               \
            sh8 vf = *reinterpret_cast<const sh8*>(                                 \
                vtb + ((2 * m + g) * 64 + 32 * cw + lj) * 8);                       \
            oacc = __builtin_amdgcn_mfma_f32_32x32x16_bf16(pa, vf, oacc, 0, 0, 0);  \
        }                                                                           \
    } while (0)

    const int alo = (row0 / 10) * 10;
    const int rmax = row0 + RPV - 1 < 1999 ? row0 + RPV - 1 : 1999;
    const int ahi = (rmax / 10) * 10 + 10;

    f32x16 oacc;
#pragma unroll
    for (int i = 0; i < 16; ++i) oacc[i] = 0.f;

    if (is_compute) {
        STAGE_KH(0); STAGE_KL(0); STAGE_VT(0);
        bar_vm_lgkm();                          // prologue
        for (int t = 0; t < NT2; ++t) {
            QK_PHASE(t);
            bar_lgkm();                          // BAR_B: Pf(t) visible
            if (t + 1 < NT2) { STAGE_KH(t + 1); STAGE_KL(t + 1); STAGE_VT(t + 1); }
            PV_PHASE(t);
            bar_vm_lgkm();                       // BAR_A: staging landed, Pf free
        }
    } else {
        const int sw = wid - 8;                  // 0..3 -> rows sw*32..+31
        bar_lgkm();                              // prologue
        for (int t = 0; t < NT2; ++t) {
            __builtin_amdgcn_s_barrier();        // BAR_B: Pf(t) ready
            __builtin_amdgcn_sched_barrier(0);
            {
                const int gj = t * 64 + lane;
                const bool colv = gj < N_TOK;
                float* ap0 = attn + abase + gj;
#pragma unroll 8
                for (int i = 0; i < 32; ++i) {
                    int r = sw * 32 + i;
                    float v = Pf[r * PFP + lane];
                    if (colv && (row0 + r) < N_TOK)
                        ap0[(size_t)r * N_TOK] = v;   // stores never waited on
                }
            }
            bar_lgkm();                          // BAR_A: Pf reads done
        }
    }
#undef STAGE_KH
#undef STAGE_KL
#undef STAGE_VT
#undef QK_PHASE
#undef PV_PHASE

    // ---- epilogue: O -> LDS -> bf16 hi/lo frags ----
    __syncthreads();                             // full drain (once)
    float* Ofull = (float*)smem;                 // [128][68] = 34,816 B
    if (is_compute) {
#pragma unroll
        for (int reg = 0; reg < 16; ++reg) {
            int rloc = wr + (reg & 3) + 8 * (reg >> 2) + 4 * g;
            Ofull[rloc * 68 + 32 * cw + lj] = oacc[reg];
        }
    }
    __syncthreads();
    for (int task = tid; task < 1024; task += 768) {
        int row = task >> 3, kq = task & 7;
        const float* op = Ofull + row * 68 + kq * 8;
        float4 a = ld4(op), c = ld4(op + 4);
        sh8 hi, lo; cvt8(a, c, hi, lo);
        int gm = b * 2048 + row0 + row;
        int mtile = gm >> 7, row128 = gm & 127;
        size_t off = ((size_t)(mtile * 64 + h * 8 + kq) * 128 + row128) * 8;
        *reinterpret_cast<sh8*>(Ohg + off) = hi;
        *reinterpret_cast<sh8*>(Olg + off) = lo;
    }
}

// ---------------------------------------------------------------------------
extern "C" void kernel_launch(void* const* d_in, const int* in_sizes, int n_in,
                              void* d_out, int out_size, void* d_ws, size_t ws_size,
                              hipStream_t stream)
{
    const float* x         = (const float*)d_in[0];
    const float* w_qkv     = (const float*)d_in[1];
    const float* w_qk_self = (const float*)d_in[2];
    const float* w_out     = (const float*)d_in[3];
    const float* b_out     = (const float*)d_in[4];

    float* out  = (float*)d_out;                       // [8036,512]
    float* attn = out + (size_t)MROWS * 512;           // [4,8,2009,2009]

    // ---- workspace layout ----
    float* Qf = (float*)d_ws;                          // 8036*512 f32
    float* Kf = Qf + (size_t)MROWS * 512;
    float* Vf = Kf + (size_t)MROWS * 512;
    float* p2 = Vf + (size_t)MROWS * 512;              // proj2 [8036*1024] f32
    unsigned short* Khg = (unsigned short*)p2;         // then Khg/Klg/Vtg (24MB)
    unsigned short* Klg = Khg + 4194304;
    unsigned short* Vtg = Klg + 4194304;
    float* proj2 = p2;
    float* after_p2 = p2 + (size_t)MROWS * 1024;
    unsigned short* xh  = (unsigned short*)after_p2;   // 8192*512 halfs
    unsigned short* xl  = xh + 4194304;
    unsigned short* Wqh = xl + 4194304;                // 512*1536
    unsigned short* Wql = Wqh + 786432;
    unsigned short* Wsh = Wql + 786432;                // 512*1024
    unsigned short* Wsl = Wsh + 524288;
    unsigned short* Woh = Wsl + 524288;                // 512*512
    unsigned short* Wol = Woh + 262144;
    float* rowinv = (float*)(Wol + 262144);            // 32*2048
    float* selfE  = rowinv + 65536;                    // 32*2000*10
    unsigned short* Ohg = (unsigned short*)Kf;         // overlay (Kf dead)
    unsigned short* Olg = Ohg + 4194304;

    const int smem_pv = 8192 + 8192 + 16384            // Kh, Kl, Vt dbuf
                      + RPV * PFP * 4                  // Pf32 (34,816)
                      + RPV * 10 * 2 + RPV * 4;        // selfS bf16 + rinv
    // = 78,656 B
    hipFuncSetAttribute((const void*)attn_pv,
                        hipFuncAttributeMaxDynamicSharedMemorySize, smem_pv);

    dim3 gx(64, 4);
    convert_x<<<gx, 256, 0, stream>>>(x, xh, xl);
    convert_w<<<768, 256, 0, stream>>>(w_qkv, w_qk_self, w_out,
                                       Wqh, Wql, Wsh, Wsl, Woh, Wol);

    dim3 g1(64, 12);
    gemm_bf16<1><<<g1, 512, 0, stream>>>(xh, xl, Wqh, Wql, Qf, nullptr);

    dim3 g2(64, 8);
    gemm_bf16<0><<<g2, 512, 0, stream>>>(xh, xl, Wsh, Wsl, proj2, nullptr);

    dim3 gs(200, 32);
    selfE_k<<<gs, 256, 0, stream>>>(proj2, selfE);

    dim3 gc(NTILES, 32);
    convert_kv<<<gc, 256, 0, stream>>>(Kf, Vf, Khg, Klg, Vtg);

    attn_rowsum<<<256, 512, 0, stream>>>(Qf, Khg, selfE, rowinv);

    attn_pv<<<512, 768, smem_pv, stream>>>(Qf, Khg, Klg, Vtg, selfE, rowinv,
                                           attn, Ohg, Olg);

    dim3 g3(64, 4);
    gemm_bf16<2><<<g3, 512, 0, stream>>>(Ohg, Olg, Woh, Wol, out, b_out);
}

// Round 15
// 472.157 us; speedup vs baseline: 1.5810x; 1.0037x over previous
//
#include <hip/hip_runtime.h>
#include <hip/hip_bf16.h>

// ---------------------------------------------------------------------------
// AgentAwareAttention (MI355X / gfx950) — Round 14: R13 producer/consumer
// with the register-spill fixed: __launch_bounds__(768, 3) gives the
// compute waves a 170-VGPR budget (R13's (768,6) capped at 85 -> oacc/frag
// spills -> 0.5GB scratch traffic, invalidating the experiment).
// 512 blocks x 768 thr (8 compute + 4 store waves), 1 block/CU, 78.7KB LDS.
// Store waves never vmcnt-wait -> write path continuously pressurized.
// ---------------------------------------------------------------------------

#define N_TOK   2009
#define NPAD    2048
#define NTILES  16           // 128-col storage tiles
#define NT2     32           // 64-col compute steps in attn_pv
#define BATCH_  4
#define HEADS_  8
#define MROWS   8036
#define SCALE_  0.125f
#define RPB_A   256          // rows per rowsum block
#define RPV     128          // rows per attn_pv block
#define PFP     68           // Pf32 pitch (f32)

typedef __attribute__((ext_vector_type(8)))  short sh8;     // 8 bf16
typedef __attribute__((ext_vector_type(16))) float f32x16;  // mfma 32x32 acc

static inline int cdiv(int a, int b) { return (a + b - 1) / b; }

__device__ __forceinline__ float4 ld4(const float* p) {
    return *reinterpret_cast<const float4*>(p);
}
__device__ __forceinline__ unsigned short f2bf(float f) {
    __hip_bfloat16 h = __float2bfloat16(f);
    return *reinterpret_cast<unsigned short*>(&h);
}
__device__ __forceinline__ float bf2f(unsigned short u) {
    return __uint_as_float(((unsigned)u) << 16);
}
__device__ __forceinline__ void cvt8(const float4& a, const float4& b, sh8& hi, sh8& lo) {
    float f[8] = {a.x, a.y, a.z, a.w, b.x, b.y, b.z, b.w};
#pragma unroll
    for (int i = 0; i < 8; ++i) {
        unsigned short h = f2bf(f[i]);
        hi[i] = (short)h;
        lo[i] = (short)f2bf(f[i] - bf2f(h));
    }
}
__device__ __forceinline__ void cvt8p(const float4& a, const float4& b, sh8& hi) {
#pragma unroll
    for (int i = 0; i < 4; ++i) {
        hi[i]     = (short)f2bf((&a.x)[i]);
        hi[4 + i] = (short)f2bf((&b.x)[i]);
    }
}
typedef const __attribute__((address_space(1))) void gas_void;
typedef __attribute__((address_space(3))) void las_void;
__device__ __forceinline__ void gll16(const void* g, void* l) {
    __builtin_amdgcn_global_load_lds((gas_void*)g, (las_void*)l, 16, 0, 0);
}

__device__ __forceinline__ void bar_lgkm() {
    asm volatile("s_waitcnt lgkmcnt(0)" ::: "memory");
    __builtin_amdgcn_sched_barrier(0);
    __builtin_amdgcn_s_barrier();
    __builtin_amdgcn_sched_barrier(0);
}
__device__ __forceinline__ void bar_vm_lgkm() {
    asm volatile("s_waitcnt vmcnt(0) lgkmcnt(0)" ::: "memory");
    __builtin_amdgcn_sched_barrier(0);
    __builtin_amdgcn_s_barrier();
    __builtin_amdgcn_sched_barrier(0);
}

// ---------------------------------------------------------------------------
// convert_x: x [4,2009,512] f32 -> xh/xl frag-major [mt 64][kc 64][row 128]x8
// ---------------------------------------------------------------------------
__global__ __launch_bounds__(256)
void convert_x(const float* __restrict__ x, unsigned short* __restrict__ xh,
               unsigned short* __restrict__ xl)
{
    const int mt = blockIdx.x;           // 0..63
    const int yq = blockIdx.y;           // 0..3
    const int w  = threadIdx.x >> 6;     // 0..3
    const int kc = threadIdx.x & 63;     // k/8
    for (int it = 0; it < 2; ++it) {
        int rg = (yq * 2 + it) * 4 + w;  // rowgroup 0..31
        sh8 hi[4], lo[4];
#pragma unroll
        for (int rr = 0; rr < 4; ++rr) {
            int row = rg * 4 + rr;
            int gm = mt * 128 + row;
            int b = gm >> 11, gr = gm & 2047;
            float4 a = make_float4(0.f, 0.f, 0.f, 0.f), c = a;
            if (gr < N_TOK) {
                const float* p = x + ((size_t)b * N_TOK + gr) * 512 + kc * 8;
                a = ld4(p); c = ld4(p + 4);
            }
            cvt8(a, c, hi[rr], lo[rr]);
        }
        size_t base = ((size_t)(mt * 64 + kc) * 128 + rg * 4) * 8;
#pragma unroll
        for (int rr = 0; rr < 4; ++rr) {
            *reinterpret_cast<sh8*>(xh + base + rr * 8) = hi[rr];
            *reinterpret_cast<sh8*>(xl + base + rr * 8) = lo[rr];
        }
    }
}

// ---------------------------------------------------------------------------
// convert_w: weights [512, N] -> hi/lo frag-major [nt][kc 64][col 128]x8
// ---------------------------------------------------------------------------
__global__ __launch_bounds__(256)
void convert_w(const float* __restrict__ wqkv, const float* __restrict__ wself,
               const float* __restrict__ wout,
               unsigned short* __restrict__ qh, unsigned short* __restrict__ ql,
               unsigned short* __restrict__ sh, unsigned short* __restrict__ sl,
               unsigned short* __restrict__ oh, unsigned short* __restrict__ ol)
{
    int cid = blockIdx.x * 256 + threadIdx.x;
    int nt_all = cid >> 13, rem = cid & 8191;
    int kc = rem >> 7, col = rem & 127;
    const float* src; unsigned short *dh, *dl; int Nn, ntl;
    if (nt_all < 12)      { src = wqkv;  dh = qh; dl = ql; Nn = 1536; ntl = nt_all; }
    else if (nt_all < 20) { src = wself; dh = sh; dl = sl; Nn = 1024; ntl = nt_all - 12; }
    else                  { src = wout;  dh = oh; dl = ol; Nn = 512;  ntl = nt_all - 20; }
    float f[8];
#pragma unroll
    for (int i = 0; i < 8; ++i)
        f[i] = src[(size_t)(kc * 8 + i) * Nn + ntl * 128 + col];
    sh8 hi, lo;
    cvt8(make_float4(f[0], f[1], f[2], f[3]), make_float4(f[4], f[5], f[6], f[7]), hi, lo);
    size_t off = ((size_t)(ntl * 64 + kc) * 128 + col) * 8;
    *reinterpret_cast<sh8*>(dh + off) = hi;
    *reinterpret_cast<sh8*>(dl + off) = lo;
}

// ---------------------------------------------------------------------------
// split-bf16 MFMA GEMM: C[8192pad x N] = A * B, K=512. BM=BN=128, BK=32 dbuf.
// ---------------------------------------------------------------------------
template<int MODE>
__global__ __launch_bounds__(512)
void gemm_bf16(const unsigned short* __restrict__ Ah, const unsigned short* __restrict__ Al,
               const unsigned short* __restrict__ Bh, const unsigned short* __restrict__ Bl,
               float* __restrict__ C, const float* __restrict__ bias)
{
    __shared__ __align__(16) unsigned short AhS[2][4096], AlS[2][4096],
                                            BhS[2][4096], BlS[2][4096];
    const int tid = threadIdx.x, lane = tid & 63, wid = tid >> 6;
    const int mt = blockIdx.x, ntile = blockIdx.y;
    const int wm = wid >> 2, wn = wid & 3;
    const int lj = lane & 31, g = lane >> 5;

    const unsigned short* Asrc_h = Ah + (size_t)mt * 65536;
    const unsigned short* Asrc_l = Al + (size_t)mt * 65536;
    const unsigned short* Bsrc_h = Bh + (size_t)ntile * 65536;
    const unsigned short* Bsrc_l = Bl + (size_t)ntile * 65536;

#define GSTAGE(BUF, S) do {                                                      \
    gll16(Asrc_h + (size_t)(S) * 4096 + tid * 8, (char*)AhS[BUF] + tid * 16);    \
    gll16(Asrc_l + (size_t)(S) * 4096 + tid * 8, (char*)AlS[BUF] + tid * 16);    \
    gll16(Bsrc_h + (size_t)(S) * 4096 + tid * 8, (char*)BhS[BUF] + tid * 16);    \
    gll16(Bsrc_l + (size_t)(S) * 4096 + tid * 8, (char*)BlS[BUF] + tid * 16);    \
} while (0)

    f32x16 acc[2];
#pragma unroll
    for (int i = 0; i < 16; ++i) { acc[0][i] = 0.f; acc[1][i] = 0.f; }

    GSTAGE(0, 0);
    for (int s = 0; s < 16; ++s) {
        const int buf = s & 1;
        __syncthreads();
        if (s + 1 < 16) GSTAGE(buf ^ 1, s + 1);
#pragma unroll
        for (int ks = 0; ks < 2; ++ks) {
            const int kcl = 2 * ks + g;
            sh8 bh = *reinterpret_cast<const sh8*>(BhS[buf] + (kcl * 128 + wn * 32 + lj) * 8);
            sh8 bl = *reinterpret_cast<const sh8*>(BlS[buf] + (kcl * 128 + wn * 32 + lj) * 8);
#pragma unroll
            for (int Mt = 0; Mt < 2; ++Mt) {
                sh8 ah = *reinterpret_cast<const sh8*>(AhS[buf] + (kcl * 128 + wm * 64 + Mt * 32 + lj) * 8);
                sh8 al = *reinterpret_cast<const sh8*>(AlS[buf] + (kcl * 128 + wm * 64 + Mt * 32 + lj) * 8);
                acc[Mt] = __builtin_amdgcn_mfma_f32_32x32x16_bf16(ah, bh, acc[Mt], 0, 0, 0);
                acc[Mt] = __builtin_amdgcn_mfma_f32_32x32x16_bf16(ah, bl, acc[Mt], 0, 0, 0);
                acc[Mt] = __builtin_amdgcn_mfma_f32_32x32x16_bf16(al, bh, acc[Mt], 0, 0, 0);
            }
        }
    }
#undef GSTAGE

#pragma unroll
    for (int Mt = 0; Mt < 2; ++Mt) {
#pragma unroll
        for (int reg = 0; reg < 16; ++reg) {
            int rloc = wm * 64 + Mt * 32 + (reg & 3) + 8 * (reg >> 2) + 4 * g;
            int gm = mt * 128 + rloc;
            int b = gm >> 11, gr = gm & 2047;
            if (gr < N_TOK) {
                int coln = ntile * 128 + wn * 32 + lj;
                float v = acc[Mt][reg];
                size_t idx;
                if (MODE == 1)
                    idx = ((size_t)(coln >> 9) * MROWS + (size_t)b * N_TOK + gr) * 512 + (coln & 511);
                else if (MODE == 0)
                    idx = ((size_t)b * N_TOK + gr) * 1024 + coln;
                else {
                    v += bias[coln];
                    idx = ((size_t)b * N_TOK + gr) * 512 + coln;
                }
                C[idx] = v;
            }
        }
    }
}

// ---------------------------------------------------------------------------
// selfE: per (bh, agent a): 10x10 exp(scale * qs_r . ks_j)
// ---------------------------------------------------------------------------
__global__ __launch_bounds__(256)
void selfE_k(const float* __restrict__ proj2, float* __restrict__ selfE)
{
    __shared__ float qs[10][64];
    __shared__ float ks[10][68];
    const int a = blockIdx.x;
    const int h = blockIdx.y & 7;
    const int b = blockIdx.y >> 3;
    const size_t rowbase = (size_t)b * N_TOK + a * 10;

    for (int i = threadIdx.x; i < 320; i += 256) {
        int r = i >> 4;
        int c = (i & 15) * 4;
        const float* src = proj2 + (rowbase + (r % 10)) * 1024
                         + (r < 10 ? 0 : 512) + h * 64 + c;
        float4 v = ld4(src);
        if (r < 10) *reinterpret_cast<float4*>(&qs[r][c]) = v;
        else        *reinterpret_cast<float4*>(&ks[r - 10][c]) = v;
    }
    __syncthreads();
    if (threadIdx.x < 100) {
        int r = threadIdx.x / 10, c = threadIdx.x % 10;
        float acc = 0.f;
#pragma unroll 8
        for (int d = 0; d < 64; ++d) acc += qs[r][d] * ks[c][d];
        int bh = b * HEADS_ + h;
        selfE[((size_t)bh * 2000 + a * 10 + r) * 10 + c] = __expf(acc * SCALE_);
    }
}

// ---------------------------------------------------------------------------
// convert K -> Khg/Klg (hi/lo, [bh][t128][kc 8][row 128]x8), V -> Vtg
// ([bh][t128][jc 16][d 64]x8)
// ---------------------------------------------------------------------------
__global__ __launch_bounds__(256)
void convert_kv(const float* __restrict__ Kf, const float* __restrict__ Vf,
                unsigned short* __restrict__ Khg, unsigned short* __restrict__ Klg,
                unsigned short* __restrict__ Vtg)
{
    __shared__ float vtile[128][66];
    const int t  = blockIdx.x;
    const int h  = blockIdx.y & 7;
    const int b  = blockIdx.y >> 3;
    const int bh = blockIdx.y;
    const size_t bN = (size_t)b * N_TOK;
    const size_t tbase = ((size_t)bh * NTILES + t) * 8192;
    const int tid = threadIdx.x;

    {
        int r = tid >> 1, q = tid & 1;
        int gj = t * 128 + r;
        float4 f[8];
        if (gj < N_TOK) {
            const float* kp = Kf + (bN + gj) * 512 + h * 64 + q * 32;
#pragma unroll
            for (int i = 0; i < 8; ++i) f[i] = ld4(kp + 4 * i);
        } else {
#pragma unroll
            for (int i = 0; i < 8; ++i) f[i] = make_float4(0.f, 0.f, 0.f, 0.f);
        }
#pragma unroll
        for (int cp = 0; cp < 4; ++cp) {
            sh8 hi, lo;
            cvt8(f[2 * cp], f[2 * cp + 1], hi, lo);
            int kc = q * 4 + cp;
            size_t off = tbase + ((size_t)kc * 128 + r) * 8;
            *reinterpret_cast<sh8*>(Khg + off) = hi;
            *reinterpret_cast<sh8*>(Klg + off) = lo;
        }
    }
    {
        int r = tid >> 1, q = tid & 1;
        int gj = t * 128 + r;
        const float* vp = Vf + (bN + gj) * 512 + h * 64 + q * 32;
#pragma unroll
        for (int i = 0; i < 8; ++i) {
            float4 v = (gj < N_TOK) ? ld4(vp + 4 * i) : make_float4(0.f, 0.f, 0.f, 0.f);
            *reinterpret_cast<float4*>(&vtile[r][q * 32 + 4 * i]) = v;
        }
    }
    __syncthreads();
    {
        int d = tid & 63, jg = tid >> 6;
#pragma unroll
        for (int jj = 0; jj < 4; ++jj) {
            int jc = jg * 4 + jj;
            sh8 pk;
#pragma unroll
            for (int i = 0; i < 8; ++i) pk[i] = (short)f2bf(vtile[jc * 8 + i][d]);
            *reinterpret_cast<sh8*>(Vtg + tbase + ((size_t)jc * 64 + d) * 8) = pk;
        }
    }
}

// ---------------------------------------------------------------------------
// pass A: rowsums (hi-only QK) -> rowinv. 256 rows/block, 256 blocks,
// XCD-local bh. Staging fully overlapped (dbuf).
// ---------------------------------------------------------------------------
__global__ __launch_bounds__(512, 2)
void attn_rowsum(const float* __restrict__ Qf,
                 const unsigned short* __restrict__ Khg,
                 const float* __restrict__ selfE,
                 float* __restrict__ rowinv)
{
    __shared__ __align__(16) unsigned short KhS[2][8192];
    __shared__ float selfS[RPB_A * 10];

    const int bid = blockIdx.x;
    const int xcd = bid & 7, idx = bid >> 3;
    const int bh  = xcd * 4 + (idx >> 3);
    const int bx  = idx & 7;
    const int h = bh & 7, b = bh >> 3;
    const int tid = threadIdx.x, lane = tid & 63, wid = tid >> 6;
    const int row0 = bx * RPB_A;
    const int wr = wid * 32;
    const size_t bN = (size_t)b * N_TOK;
    const int lj = lane & 31, g = lane >> 5;

    for (int i = tid; i < RPB_A * 10; i += 512) {
        int r = i / 10, c = i - r * 10;
        int gr = row0 + r;
        selfS[i] = (gr < 2000) ? selfE[((size_t)bh * 2000 + gr) * 10 + c] : 0.f;
    }

    sh8 qh[4];
    {
        int grow = row0 + wr + lj;
        bool val = grow < N_TOK;
        const float* qp = Qf + (bN + (val ? grow : 0)) * 512 + h * 64;
#pragma unroll
        for (int ks = 0; ks < 4; ++ks) {
            int kc = 2 * ks + g;
            float4 a = val ? ld4(qp + kc * 8)     : make_float4(0.f, 0.f, 0.f, 0.f);
            float4 c = val ? ld4(qp + kc * 8 + 4) : make_float4(0.f, 0.f, 0.f, 0.f);
            cvt8p(a, c, qh[ks]);
        }
    }

    const unsigned short* ktiles = Khg + (size_t)bh * NTILES * 8192;
#define RSTAGE(T) do {                                                          \
    const unsigned short* kt = ktiles + (size_t)(T) * 8192;                     \
    char* dst = (char*)KhS[(T) & 1];                                            \
    _Pragma("unroll") for (int i = 0; i < 2; ++i)                               \
        gll16(kt + i * 4096 + tid * 8, dst + i * 8192 + tid * 16); } while (0)

    RSTAGE(0);

    float rsacc[16];
#pragma unroll
    for (int i = 0; i < 16; ++i) rsacc[i] = 0.f;

    const int alo = (row0 / 10) * 10;
    const int rmax = row0 + RPB_A - 1 < 1999 ? row0 + RPB_A - 1 : 1999;
    const int ahi = (rmax / 10) * 10 + 10;

    for (int t = 0; t < NTILES; ++t) {
        __syncthreads();
        if (t + 1 < NTILES) RSTAGE(t + 1);
        const unsigned short* kb = KhS[t & 1];
        const bool dtile = (alo < t * 128 + 128) && (ahi > t * 128);
#pragma unroll
        for (int ct = 0; ct < 4; ++ct) {
            sh8 kf[4];
#pragma unroll
            for (int ks = 0; ks < 4; ++ks)
                kf[ks] = *reinterpret_cast<const sh8*>(kb + ((2 * ks + g) * 128 + 32 * ct + lj) * 8);
            f32x16 s;
#pragma unroll
            for (int i = 0; i < 16; ++i) s[i] = 0.f;
#pragma unroll
            for (int ks = 0; ks < 4; ++ks)
                s = __builtin_amdgcn_mfma_f32_32x32x16_bf16(qh[ks], kf[ks], s, 0, 0, 0);
            const int gj = t * 128 + 32 * ct + lj;
            if (gj < N_TOK) {
#pragma unroll
                for (int reg = 0; reg < 16; ++reg) {
                    int rloc = wr + (reg & 3) + 8 * (reg >> 2) + 4 * g;
                    int grow = row0 + rloc;
                    float e = __expf(s[reg] * SCALE_);
                    if (dtile && grow < 2000) {
                        int a0 = (grow / 10) * 10;
                        unsigned cc = (unsigned)(gj - a0);
                        if (cc < 10u) e = selfS[rloc * 10 + (int)cc];
                    }
                    rsacc[reg] += e;
                }
            }
        }
    }
#undef RSTAGE

#pragma unroll
    for (int reg = 0; reg < 16; ++reg) {
        float v = rsacc[reg];
        v += __shfl_xor(v, 1);  v += __shfl_xor(v, 2);
        v += __shfl_xor(v, 4);  v += __shfl_xor(v, 8);
        v += __shfl_xor(v, 16);
        rsacc[reg] = v;
    }
    if (lj == 0) {
#pragma unroll
        for (int reg = 0; reg < 16; ++reg) {
            int rloc = wr + (reg & 3) + 8 * (reg >> 2) + 4 * g;
            int grow = row0 + rloc;
            rowinv[(size_t)bh * NPAD + row0 + rloc] =
                (grow < N_TOK) ? 1.0f / rsacc[reg] : 0.f;
        }
    }
}

// ---------------------------------------------------------------------------
// pass B: producer/consumer at R8 geometry, spill-free. 768 threads =
// 8 compute waves (only VMEM = staging gll16) + 4 store waves (Pf->attn,
// never vmcnt-waiting). Pf single-buffered [128][68] f32. 512 blocks,
// 128 rows, 64-col steps, XCD-local bh. LDS 78,656B, 1 block/CU.
// ---------------------------------------------------------------------------
__global__ __launch_bounds__(768, 3)
void attn_pv(const float* __restrict__ Qf,
             const unsigned short* __restrict__ Khg,
             const unsigned short* __restrict__ Klg,
             const unsigned short* __restrict__ Vtg,
             const float* __restrict__ selfE,
             const float* __restrict__ rowinv,
             float* __restrict__ attn,
             unsigned short* __restrict__ Ohg, unsigned short* __restrict__ Olg)
{
    extern __shared__ __align__(16) char smem[];
    unsigned short* KhS = (unsigned short*)smem;        // 4096 halfs (8KB)
    unsigned short* KlS = KhS + 4096;                   // 4096 (8KB)
    unsigned short* VtS = KlS + 4096;                   // 2 x 4096 (16KB) dbuf
    float* Pf = (float*)(VtS + 8192);                   // 128*68 f32 (34,816B)
    unsigned short* selfS = (unsigned short*)(Pf + RPV * PFP);   // 1280 (2560B)
    float* rinvS = (float*)(selfS + RPV * 10);          // 128 f32 (512B)

    const int bid = blockIdx.x;
    const int xcd = bid & 7, idx = bid >> 3;            // idx 0..63
    const int bh  = xcd * 4 + (idx >> 4);               // 4 bh per XCD
    const int bx  = idx & 15;
    const int h = bh & 7, b = bh >> 3;
    const int tid = threadIdx.x, lane = tid & 63, wid = tid >> 6;  // wid 0..11
    const int row0 = bx * RPV;
    const size_t bN = (size_t)b * N_TOK;
    const size_t abase = ((size_t)bh * N_TOK + row0) * N_TOK;
    const int lj = lane & 31, g = lane >> 5;
    const bool is_compute = (wid < 8);
    const int wr = (wid & 3) * 32;                      // compute row group
    const int cw = (wid >> 2) & 1;                      // compute col half

    for (int i = tid; i < RPV * 10; i += 768) {
        int r = i / 10, c = i - r * 10;
        int gr = row0 + r;
        selfS[i] = (gr < 2000) ? f2bf(selfE[((size_t)bh * 2000 + gr) * 10 + c]) : 0;
    }
    if (tid < RPV) rinvS[tid] = rowinv[(size_t)bh * NPAD + row0 + tid];

    // Q frags hi+lo (compute waves only)
    sh8 qh[4], ql[4];
    if (is_compute) {
        int grow = row0 + wr + lj;
        bool val = grow < N_TOK;
        const float* qp = Qf + (bN + (val ? grow : 0)) * 512 + h * 64;
#pragma unroll
        for (int ks = 0; ks < 4; ++ks) {
            int kc = 2 * ks + g;
            float4 a = val ? ld4(qp + kc * 8)     : make_float4(0.f, 0.f, 0.f, 0.f);
            float4 c = val ? ld4(qp + kc * 8 + 4) : make_float4(0.f, 0.f, 0.f, 0.f);
            cvt8(a, c, qh[ks], ql[ks]);
        }
    }

    const unsigned short* khT = Khg + (size_t)bh * NTILES * 8192;
    const unsigned short* klT = Klg + (size_t)bh * NTILES * 8192;
    const unsigned short* vtT = Vtg + (size_t)bh * NTILES * 8192;

    // staging by compute threads (tid<512): 1 gll16 per array per thread.
#define STAGE_KH(T) gll16(khT + (size_t)((T) >> 1) * 8192                           \
        + ((size_t)(tid >> 6) * 128 + 64 * ((T) & 1) + (tid & 63)) * 8,             \
        (char*)KhS + tid * 16)
#define STAGE_KL(T) gll16(klT + (size_t)((T) >> 1) * 8192                           \
        + ((size_t)(tid >> 6) * 128 + 64 * ((T) & 1) + (tid & 63)) * 8,             \
        (char*)KlS + tid * 16)
#define STAGE_VT(T) gll16(vtT + (size_t)((T) >> 1) * 8192                           \
        + ((size_t)(8 * ((T) & 1) + (tid >> 6)) * 64 + (tid & 63)) * 8,             \
        (char*)(VtS + ((T) & 1) * 4096) + tid * 16)

#define QK_PHASE(T) do {                                                            \
        const bool dtile = (alo < (T) * 64 + 64) && (ahi > (T) * 64);               \
        sh8 kfh[4], kfl[4];                                                         \
        _Pragma("unroll") for (int ks = 0; ks < 4; ++ks) {                          \
            int off = ((2 * ks + g) * 64 + 32 * cw + lj) * 8;                       \
            kfh[ks] = *reinterpret_cast<const sh8*>(KhS + off);                     \
            kfl[ks] = *reinterpret_cast<const sh8*>(KlS + off);                     \
        }                                                                           \
        f32x16 s;                                                                   \
        _Pragma("unroll") for (int i = 0; i < 16; ++i) s[i] = 0.f;                  \
        _Pragma("unroll") for (int ks = 0; ks < 4; ++ks) {                          \
            s = __builtin_amdgcn_mfma_f32_32x32x16_bf16(qh[ks], kfh[ks], s, 0,0,0); \
            s = __builtin_amdgcn_mfma_f32_32x32x16_bf16(qh[ks], kfl[ks], s, 0,0,0); \
            s = __builtin_amdgcn_mfma_f32_32x32x16_bf16(ql[ks], kfh[ks], s, 0,0,0); \
        }                                                                           \
        const int cin = 32 * cw + lj;                                               \
        const int gj  = (T) * 64 + cin;                                             \
        const bool jv = gj < N_TOK;                                                 \
        _Pragma("unroll") for (int reg = 0; reg < 16; ++reg) {                      \
            int rowl = (reg & 3) + 8 * (reg >> 2) + 4 * g;                          \
            int rloc = wr + rowl;                                                   \
            int grow = row0 + rloc;                                                 \
            float e = 0.f;                                                          \
            if (jv && grow < N_TOK) e = __expf(s[reg] * SCALE_);                    \
            if (dtile && jv && grow < 2000) {                                       \
                int a0 = (grow / 10) * 10;                                          \
                unsigned cc = (unsigned)(gj - a0);                                  \
                if (cc < 10u) e = bf2f(selfS[rloc * 10 + (int)cc]);                 \
            }                                                                       \
            Pf[rloc * PFP + cin] = e * rinvS[rloc];                                 \
        }                                                                           \
    } while (0)

#define PV_PHASE(T) do {                                                            \
        const unsigned short* vtb = VtS + ((T) & 1) * 4096;                         \
        _Pragma("unroll") for (int m = 0; m < 4; ++m) {                             \
            const float* pp = &Pf[(wr + lj) * PFP + 16 * m + 8 * g];                \
            float4 a = ld4(pp), b4 = ld4(pp + 4);                                   \
            sh8 pa; cvt8p(a, b4, pa);                                               \
            sh8 vf = *reinterpret_cast<const sh8*>(                                 \
                vtb + ((2 * m + g) * 64 + 32 * cw + lj) * 8);                       \
            oacc = __builtin_amdgcn_mfma_f32_32x32x16_bf16(pa, vf, oacc, 0, 0, 0);  \
        }                                                                           \
    } while (0)

    const int alo = (row0 / 10) * 10;
    const int rmax = row0 + RPV - 1 < 1999 ? row0 + RPV - 1 : 1999;
    const int ahi = (rmax / 10) * 10 + 10;

    f32x16 oacc;
#pragma unroll
    for (int i = 0; i < 16; ++i) oacc[i] = 0.f;

    if (is_compute) {
        STAGE_KH(0); STAGE_KL(0); STAGE_VT(0);
        bar_vm_lgkm();                          // prologue
        for (int t = 0; t < NT2; ++t) {
            QK_PHASE(t);
            bar_lgkm();                          // BAR_B: Pf(t) visible
            if (t + 1 < NT2) { STAGE_KH(t + 1); STAGE_KL(t + 1); STAGE_VT(t + 1); }
            PV_PHASE(t);
            bar_vm_lgkm();                       // BAR_A: staging landed, Pf free
        }
    } else {
        const int sw = wid - 8;                  // 0..3 -> rows sw*32..+31
        bar_lgkm();                              // prologue
        for (int t = 0; t < NT2; ++t) {
            __builtin_amdgcn_s_barrier();        // BAR_B: Pf(t) ready
            __builtin_amdgcn_sched_barrier(0);
            {
                const int gj = t * 64 + lane;
                const bool colv = gj < N_TOK;
                float* ap0 = attn + abase + gj;
#pragma unroll 8
                for (int i = 0; i < 32; ++i) {
                    int r = sw * 32 + i;
                    float v = Pf[r * PFP + lane];
                    if (colv && (row0 + r) < N_TOK)
                        ap0[(size_t)r * N_TOK] = v;   // stores never waited on
                }
            }
            bar_lgkm();                          // BAR_A: Pf reads done
        }
    }
#undef STAGE_KH
#undef STAGE_KL
#undef STAGE_VT
#undef QK_PHASE
#undef PV_PHASE

    // ---- epilogue: O -> LDS -> bf16 hi/lo frags ----
    __syncthreads();                             // full drain (once)
    float* Ofull = (float*)smem;                 // [128][68] = 34,816 B
    if (is_compute) {
#pragma unroll
        for (int reg = 0; reg < 16; ++reg) {
            int rloc = wr + (reg & 3) + 8 * (reg >> 2) + 4 * g;
            Ofull[rloc * 68 + 32 * cw + lj] = oacc[reg];
        }
    }
    __syncthreads();
    for (int task = tid; task < 1024; task += 768) {
        int row = task >> 3, kq = task & 7;
        const float* op = Ofull + row * 68 + kq * 8;
        float4 a = ld4(op), c = ld4(op + 4);
        sh8 hi, lo; cvt8(a, c, hi, lo);
        int gm = b * 2048 + row0 + row;
        int mtile = gm >> 7, row128 = gm & 127;
        size_t off = ((size_t)(mtile * 64 + h * 8 + kq) * 128 + row128) * 8;
        *reinterpret_cast<sh8*>(Ohg + off) = hi;
        *reinterpret_cast<sh8*>(Olg + off) = lo;
    }
}

// ---------------------------------------------------------------------------
extern "C" void kernel_launch(void* const* d_in, const int* in_sizes, int n_in,
                              void* d_out, int out_size, void* d_ws, size_t ws_size,
                              hipStream_t stream)
{
    const float* x         = (const float*)d_in[0];
    const float* w_qkv     = (const float*)d_in[1];
    const float* w_qk_self = (const float*)d_in[2];
    const float* w_out     = (const float*)d_in[3];
    const float* b_out     = (const float*)d_in[4];

    float* out  = (float*)d_out;                       // [8036,512]
    float* attn = out + (size_t)MROWS * 512;           // [4,8,2009,2009]

    // ---- workspace layout ----
    float* Qf = (float*)d_ws;                          // 8036*512 f32
    float* Kf = Qf + (size_t)MROWS * 512;
    float* Vf = Kf + (size_t)MROWS * 512;
    float* p2 = Vf + (size_t)MROWS * 512;              // proj2 [8036*1024] f32
    unsigned short* Khg = (unsigned short*)p2;         // then Khg/Klg/Vtg (24MB)
    unsigned short* Klg = Khg + 4194304;
    unsigned short* Vtg = Klg + 4194304;
    float* proj2 = p2;
    float* after_p2 = p2 + (size_t)MROWS * 1024;
    unsigned short* xh  = (unsigned short*)after_p2;   // 8192*512 halfs
    unsigned short* xl  = xh + 4194304;
    unsigned short* Wqh = xl + 4194304;                // 512*1536
    unsigned short* Wql = Wqh + 786432;
    unsigned short* Wsh = Wql + 786432;                // 512*1024
    unsigned short* Wsl = Wsh + 524288;
    unsigned short* Woh = Wsl + 524288;                // 512*512
    unsigned short* Wol = Woh + 262144;
    float* rowinv = (float*)(Wol + 262144);            // 32*2048
    float* selfE  = rowinv + 65536;                    // 32*2000*10
    unsigned short* Ohg = (unsigned short*)Kf;         // overlay (Kf dead)
    unsigned short* Olg = Ohg + 4194304;

    const int smem_pv = 8192 + 8192 + 16384            // Kh, Kl, Vt dbuf
                      + RPV * PFP * 4                  // Pf32 (34,816)
                      + RPV * 10 * 2 + RPV * 4;        // selfS bf16 + rinv
    // = 78,656 B
    hipFuncSetAttribute((const void*)attn_pv,
                        hipFuncAttributeMaxDynamicSharedMemorySize, smem_pv);

    dim3 gx(64, 4);
    convert_x<<<gx, 256, 0, stream>>>(x, xh, xl);
    convert_w<<<768, 256, 0, stream>>>(w_qkv, w_qk_self, w_out,
                                       Wqh, Wql, Wsh, Wsl, Woh, Wol);

    dim3 g1(64, 12);
    gemm_bf16<1><<<g1, 512, 0, stream>>>(xh, xl, Wqh, Wql, Qf, nullptr);

    dim3 g2(64, 8);
    gemm_bf16<0><<<g2, 512, 0, stream>>>(xh, xl, Wsh, Wsl, proj2, nullptr);

    dim3 gs(200, 32);
    selfE_k<<<gs, 256, 0, stream>>>(proj2, selfE);

    dim3 gc(NTILES, 32);
    convert_kv<<<gc, 256, 0, stream>>>(Kf, Vf, Khg, Klg, Vtg);

    attn_rowsum<<<256, 512, 0, stream>>>(Qf, Khg, selfE, rowinv);

    attn_pv<<<512, 768, smem_pv, stream>>>(Qf, Khg, Klg, Vtg, selfE, rowinv,
                                           attn, Ohg, Olg);

    dim3 g3(64, 4);
    gemm_bf16<2><<<g3, 512, 0, stream>>>(Ohg, Olg, Woh, Wol, out, b_out);
}

// Round 16
// 442.570 us; speedup vs baseline: 1.6867x; 1.0669x over previous
//
#include <hip/hip_runtime.h>
#include <hip/hip_bf16.h>

// ---------------------------------------------------------------------------
// AgentAwareAttention (MI355X / gfx950) — Final: revert to Round-8 best
// (460 µs). 2 blocks/CU attn_pv, f32-LDS P tile, full-line dwordx4 normal
// attn stores, PV converts P from f32 LDS on the fly. XCD-local bh.
// R9-R14 ablations (counted vmcnt / nt / coalescing shape / occupancy /
// producer-consumer) were all neutral-or-worse; this is the ceiling of the
// mixed compute+store structure at HIP source level.
// ---------------------------------------------------------------------------

#define N_TOK   2009
#define NPAD    2048
#define NTILES  16           // 128-col storage tiles
#define NT2     32           // 64-col compute steps in attn_pv
#define BATCH_  4
#define HEADS_  8
#define MROWS   8036
#define SCALE_  0.125f
#define RPB_A   256          // rows per rowsum block
#define RPV     128          // rows per attn_pv block
#define PFP     68           // Pf32 pitch (f32): 272B, 16B-aligned rows

typedef __attribute__((ext_vector_type(8)))  short sh8;     // 8 bf16
typedef __attribute__((ext_vector_type(16))) float f32x16;  // mfma 32x32 acc

static inline int cdiv(int a, int b) { return (a + b - 1) / b; }

__device__ __forceinline__ float4 ld4(const float* p) {
    return *reinterpret_cast<const float4*>(p);
}
__device__ __forceinline__ unsigned short f2bf(float f) {
    __hip_bfloat16 h = __float2bfloat16(f);
    return *reinterpret_cast<unsigned short*>(&h);
}
__device__ __forceinline__ float bf2f(unsigned short u) {
    return __uint_as_float(((unsigned)u) << 16);
}
__device__ __forceinline__ void cvt8(const float4& a, const float4& b, sh8& hi, sh8& lo) {
    float f[8] = {a.x, a.y, a.z, a.w, b.x, b.y, b.z, b.w};
#pragma unroll
    for (int i = 0; i < 8; ++i) {
        unsigned short h = f2bf(f[i]);
        hi[i] = (short)h;
        lo[i] = (short)f2bf(f[i] - bf2f(h));
    }
}
__device__ __forceinline__ void cvt8p(const float4& a, const float4& b, sh8& hi) {
#pragma unroll
    for (int i = 0; i < 4; ++i) {
        hi[i]     = (short)f2bf((&a.x)[i]);
        hi[4 + i] = (short)f2bf((&b.x)[i]);
    }
}
typedef const __attribute__((address_space(1))) void gas_void;
typedef __attribute__((address_space(3))) void las_void;
__device__ __forceinline__ void gll16(const void* g, void* l) {
    __builtin_amdgcn_global_load_lds((gas_void*)g, (las_void*)l, 16, 0, 0);
}

// ---------------------------------------------------------------------------
// convert_x: x [4,2009,512] f32 -> xh/xl frag-major [mt 64][kc 64][row 128]x8
// ---------------------------------------------------------------------------
__global__ __launch_bounds__(256)
void convert_x(const float* __restrict__ x, unsigned short* __restrict__ xh,
               unsigned short* __restrict__ xl)
{
    const int mt = blockIdx.x;           // 0..63
    const int yq = blockIdx.y;           // 0..3
    const int w  = threadIdx.x >> 6;     // 0..3
    const int kc = threadIdx.x & 63;     // k/8
    for (int it = 0; it < 2; ++it) {
        int rg = (yq * 2 + it) * 4 + w;  // rowgroup 0..31
        sh8 hi[4], lo[4];
#pragma unroll
        for (int rr = 0; rr < 4; ++rr) {
            int row = rg * 4 + rr;
            int gm = mt * 128 + row;
            int b = gm >> 11, gr = gm & 2047;
            float4 a = make_float4(0.f, 0.f, 0.f, 0.f), c = a;
            if (gr < N_TOK) {
                const float* p = x + ((size_t)b * N_TOK + gr) * 512 + kc * 8;
                a = ld4(p); c = ld4(p + 4);
            }
            cvt8(a, c, hi[rr], lo[rr]);
        }
        size_t base = ((size_t)(mt * 64 + kc) * 128 + rg * 4) * 8;
#pragma unroll
        for (int rr = 0; rr < 4; ++rr) {
            *reinterpret_cast<sh8*>(xh + base + rr * 8) = hi[rr];
            *reinterpret_cast<sh8*>(xl + base + rr * 8) = lo[rr];
        }
    }
}

// ---------------------------------------------------------------------------
// convert_w: weights [512, N] -> hi/lo frag-major [nt][kc 64][col 128]x8
// ---------------------------------------------------------------------------
__global__ __launch_bounds__(256)
void convert_w(const float* __restrict__ wqkv, const float* __restrict__ wself,
               const float* __restrict__ wout,
               unsigned short* __restrict__ qh, unsigned short* __restrict__ ql,
               unsigned short* __restrict__ sh, unsigned short* __restrict__ sl,
               unsigned short* __restrict__ oh, unsigned short* __restrict__ ol)
{
    int cid = blockIdx.x * 256 + threadIdx.x;
    int nt_all = cid >> 13, rem = cid & 8191;
    int kc = rem >> 7, col = rem & 127;
    const float* src; unsigned short *dh, *dl; int Nn, ntl;
    if (nt_all < 12)      { src = wqkv;  dh = qh; dl = ql; Nn = 1536; ntl = nt_all; }
    else if (nt_all < 20) { src = wself; dh = sh; dl = sl; Nn = 1024; ntl = nt_all - 12; }
    else                  { src = wout;  dh = oh; dl = ol; Nn = 512;  ntl = nt_all - 20; }
    float f[8];
#pragma unroll
    for (int i = 0; i < 8; ++i)
        f[i] = src[(size_t)(kc * 8 + i) * Nn + ntl * 128 + col];
    sh8 hi, lo;
    cvt8(make_float4(f[0], f[1], f[2], f[3]), make_float4(f[4], f[5], f[6], f[7]), hi, lo);
    size_t off = ((size_t)(ntl * 64 + kc) * 128 + col) * 8;
    *reinterpret_cast<sh8*>(dh + off) = hi;
    *reinterpret_cast<sh8*>(dl + off) = lo;
}

// ---------------------------------------------------------------------------
// split-bf16 MFMA GEMM: C[8192pad x N] = A * B, K=512. BM=BN=128, BK=32 dbuf.
// ---------------------------------------------------------------------------
template<int MODE>
__global__ __launch_bounds__(512)
void gemm_bf16(const unsigned short* __restrict__ Ah, const unsigned short* __restrict__ Al,
               const unsigned short* __restrict__ Bh, const unsigned short* __restrict__ Bl,
               float* __restrict__ C, const float* __restrict__ bias)
{
    __shared__ __align__(16) unsigned short AhS[2][4096], AlS[2][4096],
                                            BhS[2][4096], BlS[2][4096];
    const int tid = threadIdx.x, lane = tid & 63, wid = tid >> 6;
    const int mt = blockIdx.x, ntile = blockIdx.y;
    const int wm = wid >> 2, wn = wid & 3;
    const int lj = lane & 31, g = lane >> 5;

    const unsigned short* Asrc_h = Ah + (size_t)mt * 65536;
    const unsigned short* Asrc_l = Al + (size_t)mt * 65536;
    const unsigned short* Bsrc_h = Bh + (size_t)ntile * 65536;
    const unsigned short* Bsrc_l = Bl + (size_t)ntile * 65536;

#define GSTAGE(BUF, S) do {                                                      \
    gll16(Asrc_h + (size_t)(S) * 4096 + tid * 8, (char*)AhS[BUF] + tid * 16);    \
    gll16(Asrc_l + (size_t)(S) * 4096 + tid * 8, (char*)AlS[BUF] + tid * 16);    \
    gll16(Bsrc_h + (size_t)(S) * 4096 + tid * 8, (char*)BhS[BUF] + tid * 16);    \
    gll16(Bsrc_l + (size_t)(S) * 4096 + tid * 8, (char*)BlS[BUF] + tid * 16);    \
} while (0)

    f32x16 acc[2];
#pragma unroll
    for (int i = 0; i < 16; ++i) { acc[0][i] = 0.f; acc[1][i] = 0.f; }

    GSTAGE(0, 0);
    for (int s = 0; s < 16; ++s) {
        const int buf = s & 1;
        __syncthreads();
        if (s + 1 < 16) GSTAGE(buf ^ 1, s + 1);
#pragma unroll
        for (int ks = 0; ks < 2; ++ks) {
            const int kcl = 2 * ks + g;
            sh8 bh = *reinterpret_cast<const sh8*>(BhS[buf] + (kcl * 128 + wn * 32 + lj) * 8);
            sh8 bl = *reinterpret_cast<const sh8*>(BlS[buf] + (kcl * 128 + wn * 32 + lj) * 8);
#pragma unroll
            for (int Mt = 0; Mt < 2; ++Mt) {
                sh8 ah = *reinterpret_cast<const sh8*>(AhS[buf] + (kcl * 128 + wm * 64 + Mt * 32 + lj) * 8);
                sh8 al = *reinterpret_cast<const sh8*>(AlS[buf] + (kcl * 128 + wm * 64 + Mt * 32 + lj) * 8);
                acc[Mt] = __builtin_amdgcn_mfma_f32_32x32x16_bf16(ah, bh, acc[Mt], 0, 0, 0);
                acc[Mt] = __builtin_amdgcn_mfma_f32_32x32x16_bf16(ah, bl, acc[Mt], 0, 0, 0);
                acc[Mt] = __builtin_amdgcn_mfma_f32_32x32x16_bf16(al, bh, acc[Mt], 0, 0, 0);
            }
        }
    }
#undef GSTAGE

#pragma unroll
    for (int Mt = 0; Mt < 2; ++Mt) {
#pragma unroll
        for (int reg = 0; reg < 16; ++reg) {
            int rloc = wm * 64 + Mt * 32 + (reg & 3) + 8 * (reg >> 2) + 4 * g;
            int gm = mt * 128 + rloc;
            int b = gm >> 11, gr = gm & 2047;
            if (gr < N_TOK) {
                int coln = ntile * 128 + wn * 32 + lj;
                float v = acc[Mt][reg];
                size_t idx;
                if (MODE == 1)
                    idx = ((size_t)(coln >> 9) * MROWS + (size_t)b * N_TOK + gr) * 512 + (coln & 511);
                else if (MODE == 0)
                    idx = ((size_t)b * N_TOK + gr) * 1024 + coln;
                else {
                    v += bias[coln];
                    idx = ((size_t)b * N_TOK + gr) * 512 + coln;
                }
                C[idx] = v;
            }
        }
    }
}

// ---------------------------------------------------------------------------
// selfE: per (bh, agent a): 10x10 exp(scale * qs_r . ks_j)
// ---------------------------------------------------------------------------
__global__ __launch_bounds__(256)
void selfE_k(const float* __restrict__ proj2, float* __restrict__ selfE)
{
    __shared__ float qs[10][64];
    __shared__ float ks[10][68];
    const int a = blockIdx.x;
    const int h = blockIdx.y & 7;
    const int b = blockIdx.y >> 3;
    const size_t rowbase = (size_t)b * N_TOK + a * 10;

    for (int i = threadIdx.x; i < 320; i += 256) {
        int r = i >> 4;
        int c = (i & 15) * 4;
        const float* src = proj2 + (rowbase + (r % 10)) * 1024
                         + (r < 10 ? 0 : 512) + h * 64 + c;
        float4 v = ld4(src);
        if (r < 10) *reinterpret_cast<float4*>(&qs[r][c]) = v;
        else        *reinterpret_cast<float4*>(&ks[r - 10][c]) = v;
    }
    __syncthreads();
    if (threadIdx.x < 100) {
        int r = threadIdx.x / 10, c = threadIdx.x % 10;
        float acc = 0.f;
#pragma unroll 8
        for (int d = 0; d < 64; ++d) acc += qs[r][d] * ks[c][d];
        int bh = b * HEADS_ + h;
        selfE[((size_t)bh * 2000 + a * 10 + r) * 10 + c] = __expf(acc * SCALE_);
    }
}

// ---------------------------------------------------------------------------
// convert K -> Khg/Klg (hi/lo, [bh][t128][kc 8][row 128]x8), V -> Vtg
// ([bh][t128][jc 16][d 64]x8)
// ---------------------------------------------------------------------------
__global__ __launch_bounds__(256)
void convert_kv(const float* __restrict__ Kf, const float* __restrict__ Vf,
                unsigned short* __restrict__ Khg, unsigned short* __restrict__ Klg,
                unsigned short* __restrict__ Vtg)
{
    __shared__ float vtile[128][66];
    const int t  = blockIdx.x;
    const int h  = blockIdx.y & 7;
    const int b  = blockIdx.y >> 3;
    const int bh = blockIdx.y;
    const size_t bN = (size_t)b * N_TOK;
    const size_t tbase = ((size_t)bh * NTILES + t) * 8192;
    const int tid = threadIdx.x;

    {
        int r = tid >> 1, q = tid & 1;
        int gj = t * 128 + r;
        float4 f[8];
        if (gj < N_TOK) {
            const float* kp = Kf + (bN + gj) * 512 + h * 64 + q * 32;
#pragma unroll
            for (int i = 0; i < 8; ++i) f[i] = ld4(kp + 4 * i);
        } else {
#pragma unroll
            for (int i = 0; i < 8; ++i) f[i] = make_float4(0.f, 0.f, 0.f, 0.f);
        }
#pragma unroll
        for (int cp = 0; cp < 4; ++cp) {
            sh8 hi, lo;
            cvt8(f[2 * cp], f[2 * cp + 1], hi, lo);
            int kc = q * 4 + cp;
            size_t off = tbase + ((size_t)kc * 128 + r) * 8;
            *reinterpret_cast<sh8*>(Khg + off) = hi;
            *reinterpret_cast<sh8*>(Klg + off) = lo;
        }
    }
    {
        int r = tid >> 1, q = tid & 1;
        int gj = t * 128 + r;
        const float* vp = Vf + (bN + gj) * 512 + h * 64 + q * 32;
#pragma unroll
        for (int i = 0; i < 8; ++i) {
            float4 v = (gj < N_TOK) ? ld4(vp + 4 * i) : make_float4(0.f, 0.f, 0.f, 0.f);
            *reinterpret_cast<float4*>(&vtile[r][q * 32 + 4 * i]) = v;
        }
    }
    __syncthreads();
    {
        int d = tid & 63, jg = tid >> 6;
#pragma unroll
        for (int jj = 0; jj < 4; ++jj) {
            int jc = jg * 4 + jj;
            sh8 pk;
#pragma unroll
            for (int i = 0; i < 8; ++i) pk[i] = (short)f2bf(vtile[jc * 8 + i][d]);
            *reinterpret_cast<sh8*>(Vtg + tbase + ((size_t)jc * 64 + d) * 8) = pk;
        }
    }
}

// ---------------------------------------------------------------------------
// pass A: rowsums (hi-only QK) -> rowinv. 256 rows/block, 256 blocks,
// XCD-local bh. Staging fully overlapped (dbuf).
// ---------------------------------------------------------------------------
__global__ __launch_bounds__(512, 2)
void attn_rowsum(const float* __restrict__ Qf,
                 const unsigned short* __restrict__ Khg,
                 const float* __restrict__ selfE,
                 float* __restrict__ rowinv)
{
    __shared__ __align__(16) unsigned short KhS[2][8192];
    __shared__ float selfS[RPB_A * 10];

    const int bid = blockIdx.x;
    const int xcd = bid & 7, idx = bid >> 3;
    const int bh  = xcd * 4 + (idx >> 3);
    const int bx  = idx & 7;
    const int h = bh & 7, b = bh >> 3;
    const int tid = threadIdx.x, lane = tid & 63, wid = tid >> 6;
    const int row0 = bx * RPB_A;
    const int wr = wid * 32;
    const size_t bN = (size_t)b * N_TOK;
    const int lj = lane & 31, g = lane >> 5;

    for (int i = tid; i < RPB_A * 10; i += 512) {
        int r = i / 10, c = i - r * 10;
        int gr = row0 + r;
        selfS[i] = (gr < 2000) ? selfE[((size_t)bh * 2000 + gr) * 10 + c] : 0.f;
    }

    sh8 qh[4];
    {
        int grow = row0 + wr + lj;
        bool val = grow < N_TOK;
        const float* qp = Qf + (bN + (val ? grow : 0)) * 512 + h * 64;
#pragma unroll
        for (int ks = 0; ks < 4; ++ks) {
            int kc = 2 * ks + g;
            float4 a = val ? ld4(qp + kc * 8)     : make_float4(0.f, 0.f, 0.f, 0.f);
            float4 c = val ? ld4(qp + kc * 8 + 4) : make_float4(0.f, 0.f, 0.f, 0.f);
            cvt8p(a, c, qh[ks]);
        }
    }

    const unsigned short* ktiles = Khg + (size_t)bh * NTILES * 8192;
#define RSTAGE(T) do {                                                          \
    const unsigned short* kt = ktiles + (size_t)(T) * 8192;                     \
    char* dst = (char*)KhS[(T) & 1];                                            \
    _Pragma("unroll") for (int i = 0; i < 2; ++i)                               \
        gll16(kt + i * 4096 + tid * 8, dst + i * 8192 + tid * 16); } while (0)

    RSTAGE(0);

    float rsacc[16];
#pragma unroll
    for (int i = 0; i < 16; ++i) rsacc[i] = 0.f;

    const int alo = (row0 / 10) * 10;
    const int rmax = row0 + RPB_A - 1 < 1999 ? row0 + RPB_A - 1 : 1999;
    const int ahi = (rmax / 10) * 10 + 10;

    for (int t = 0; t < NTILES; ++t) {
        __syncthreads();
        if (t + 1 < NTILES) RSTAGE(t + 1);
        const unsigned short* kb = KhS[t & 1];
        const bool dtile = (alo < t * 128 + 128) && (ahi > t * 128);
#pragma unroll
        for (int ct = 0; ct < 4; ++ct) {
            sh8 kf[4];
#pragma unroll
            for (int ks = 0; ks < 4; ++ks)
                kf[ks] = *reinterpret_cast<const sh8*>(kb + ((2 * ks + g) * 128 + 32 * ct + lj) * 8);
            f32x16 s;
#pragma unroll
            for (int i = 0; i < 16; ++i) s[i] = 0.f;
#pragma unroll
            for (int ks = 0; ks < 4; ++ks)
                s = __builtin_amdgcn_mfma_f32_32x32x16_bf16(qh[ks], kf[ks], s, 0, 0, 0);
            const int gj = t * 128 + 32 * ct + lj;
            if (gj < N_TOK) {
#pragma unroll
                for (int reg = 0; reg < 16; ++reg) {
                    int rloc = wr + (reg & 3) + 8 * (reg >> 2) + 4 * g;
                    int grow = row0 + rloc;
                    float e = __expf(s[reg] * SCALE_);
                    if (dtile && grow < 2000) {
                        int a0 = (grow / 10) * 10;
                        unsigned cc = (unsigned)(gj - a0);
                        if (cc < 10u) e = selfS[rloc * 10 + (int)cc];
                    }
                    rsacc[reg] += e;
                }
            }
        }
    }
#undef RSTAGE

#pragma unroll
    for (int reg = 0; reg < 16; ++reg) {
        float v = rsacc[reg];
        v += __shfl_xor(v, 1);  v += __shfl_xor(v, 2);
        v += __shfl_xor(v, 4);  v += __shfl_xor(v, 8);
        v += __shfl_xor(v, 16);
        rsacc[reg] = v;
    }
    if (lj == 0) {
#pragma unroll
        for (int reg = 0; reg < 16; ++reg) {
            int rloc = wr + (reg & 3) + 8 * (reg >> 2) + 4 * g;
            int grow = row0 + rloc;
            rowinv[(size_t)bh * NPAD + row0 + rloc] =
                (grow < N_TOK) ? 1.0f / rsacc[reg] : 0.f;
        }
    }
}

// ---------------------------------------------------------------------------
// pass B: split-bf16 QK -> P (f32 LDS) -> attn (aligned dwordx4, normal
// stores); PV (P cvt'd from f32 LDS) -> Ohg/Olg.
// 512 blocks (2/CU), 128 rows/block, 64-col steps, XCD-local bh.
// LDS 70,656 B: Kh 8K | Kl 8K | Vt dbuf 16K | Pf32 34.8K | selfS 2.5K | rinv .5K
// ---------------------------------------------------------------------------
__global__ __launch_bounds__(512, 2)
void attn_pv(const float* __restrict__ Qf,
             const unsigned short* __restrict__ Khg,
             const unsigned short* __restrict__ Klg,
             const unsigned short* __restrict__ Vtg,
             const float* __restrict__ selfE,
             const float* __restrict__ rowinv,
             float* __restrict__ attn,
             unsigned short* __restrict__ Ohg, unsigned short* __restrict__ Olg)
{
    extern __shared__ __align__(16) char smem[];
    unsigned short* KhS = (unsigned short*)smem;        // 4096 halfs (8KB)
    unsigned short* KlS = KhS + 4096;                   // 4096 (8KB)
    unsigned short* VtS = KlS + 4096;                   // 2 x 4096 (16KB) dbuf
    float* Pf = (float*)(VtS + 8192);                   // 128*68 f32 (34,816B)
    unsigned short* selfS = (unsigned short*)(Pf + RPV * PFP);   // 1280 (2560B)
    float* rinvS = (float*)(selfS + RPV * 10);          // 128 f32 (512B)

    const int bid = blockIdx.x;
    const int xcd = bid & 7, idx = bid >> 3;            // idx 0..63
    const int bh  = xcd * 4 + (idx >> 4);               // 4 bh per XCD
    const int bx  = idx & 15;
    const int h = bh & 7, b = bh >> 3;
    const int tid = threadIdx.x, lane = tid & 63, wid = tid >> 6;
    const int row0 = bx * RPV;
    const int wr = (wid & 3) * 32;                      // wave row group
    const int cw = wid >> 2;                            // wave col half (0/1)
    const size_t bN = (size_t)b * N_TOK;
    const size_t abase = ((size_t)bh * N_TOK + row0) * N_TOK;
    const int lj = lane & 31, g = lane >> 5;

    for (int i = tid; i < RPV * 10; i += 512) {
        int r = i / 10, c = i - r * 10;
        int gr = row0 + r;
        selfS[i] = (gr < 2000) ? f2bf(selfE[((size_t)bh * 2000 + gr) * 10 + c]) : 0;
    }
    if (tid < RPV) rinvS[tid] = rowinv[(size_t)bh * NPAD + row0 + tid];

    // Q frags hi+lo (wave rows wr..wr+31)
    sh8 qh[4], ql[4];
    {
        int grow = row0 + wr + lj;
        bool val = grow < N_TOK;
        const float* qp = Qf + (bN + (val ? grow : 0)) * 512 + h * 64;
#pragma unroll
        for (int ks = 0; ks < 4; ++ks) {
            int kc = 2 * ks + g;
            float4 a = val ? ld4(qp + kc * 8)     : make_float4(0.f, 0.f, 0.f, 0.f);
            float4 c = val ? ld4(qp + kc * 8 + 4) : make_float4(0.f, 0.f, 0.f, 0.f);
            cvt8(a, c, qh[ks], ql[ks]);
        }
    }

    const unsigned short* khT = Khg + (size_t)bh * NTILES * 8192;
    const unsigned short* klT = Klg + (size_t)bh * NTILES * 8192;
    const unsigned short* vtT = Vtg + (size_t)bh * NTILES * 8192;

    // 64-col step T: storage tile T>>1, half T&1. 1 gll16/thread/array.
#define STAGE_KH(T) gll16(khT + (size_t)((T) >> 1) * 8192                           \
        + ((size_t)(tid >> 6) * 128 + 64 * ((T) & 1) + (tid & 63)) * 8,             \
        (char*)KhS + tid * 16)
#define STAGE_KL(T) gll16(klT + (size_t)((T) >> 1) * 8192                           \
        + ((size_t)(tid >> 6) * 128 + 64 * ((T) & 1) + (tid & 63)) * 8,             \
        (char*)KlS + tid * 16)
#define STAGE_VT(T) gll16(vtT + (size_t)((T) >> 1) * 8192                           \
        + ((size_t)(8 * ((T) & 1) + (tid >> 6)) * 64 + (tid & 63)) * 8,             \
        (char*)(VtS + ((T) & 1) * 4096) + tid * 16)

    STAGE_KH(0); STAGE_KL(0); STAGE_VT(0);

    const int alo = (row0 / 10) * 10;
    const int rmax = row0 + RPV - 1 < 1999 ? row0 + RPV - 1 : 1999;
    const int ahi = (rmax / 10) * 10 + 10;

    f32x16 oacc;
#pragma unroll
    for (int i = 0; i < 16; ++i) oacc[i] = 0.f;

    __syncthreads();                           // prologue staging drained

    for (int t = 0; t < NT2; ++t) {
        const bool dtile = (alo < t * 64 + 64) && (ahi > t * 64);

        // ---- phase A: QK (rows wr, cols 32*cw..) ----
        sh8 kfh[4], kfl[4];
#pragma unroll
        for (int ks = 0; ks < 4; ++ks) {
            int off = ((2 * ks + g) * 64 + 32 * cw + lj) * 8;
            kfh[ks] = *reinterpret_cast<const sh8*>(KhS + off);
            kfl[ks] = *reinterpret_cast<const sh8*>(KlS + off);
        }
        f32x16 s;
#pragma unroll
        for (int i = 0; i < 16; ++i) s[i] = 0.f;
#pragma unroll
        for (int ks = 0; ks < 4; ++ks) {
            s = __builtin_amdgcn_mfma_f32_32x32x16_bf16(qh[ks], kfh[ks], s, 0, 0, 0);
            s = __builtin_amdgcn_mfma_f32_32x32x16_bf16(qh[ks], kfl[ks], s, 0, 0, 0);
            s = __builtin_amdgcn_mfma_f32_32x32x16_bf16(ql[ks], kfh[ks], s, 0, 0, 0);
        }
        const int cin = 32 * cw + lj;
        const int gj  = t * 64 + cin;
        const bool jv = gj < N_TOK;
#pragma unroll
        for (int reg = 0; reg < 16; ++reg) {
            int rowl = (reg & 3) + 8 * (reg >> 2) + 4 * g;
            int rloc = wr + rowl;
            int grow = row0 + rloc;
            float e = 0.f;
            if (jv && grow < N_TOK) e = __expf(s[reg] * SCALE_);
            if (dtile && jv && grow < 2000) {
                int a0 = (grow / 10) * 10;
                unsigned cc = (unsigned)(gj - a0);
                if (cc < 10u) e = bf2f(selfS[rloc * 10 + (int)cc]);
            }
            Pf[rloc * PFP + cin] = e * rinvS[rloc];
        }
        __syncthreads();                       // B1: Pf visible; Kh/Kl free

        // ---- phase B: stage next, PV, aligned attn stores ----
        if (t + 1 < NT2) { STAGE_KH(t + 1); STAGE_KL(t + 1); STAGE_VT(t + 1); }
        const unsigned short* vtb = VtS + (t & 1) * 4096;
#pragma unroll
        for (int m = 0; m < 4; ++m) {
            const float* pp = &Pf[(wr + lj) * PFP + 16 * m + 8 * g];
            float4 a = ld4(pp), b4 = ld4(pp + 4);
            sh8 pa; cvt8p(a, b4, pa);
            sh8 vf = *reinterpret_cast<const sh8*>(vtb + ((2 * m + g) * 64 + 32 * cw + lj) * 8);
            oacc = __builtin_amdgcn_mfma_f32_32x32x16_bf16(pa, vf, oacc, 0, 0, 0);
        }
        // store phase: contiguous 256B/row dwordx4 normal stores
        {
            const int c4  = (tid & 15) * 4;
            const int gj0 = t * 64 + c4;
#pragma unroll
            for (int it = 0; it < 4; ++it) {
                int r = it * 32 + (tid >> 4);
                int grow = row0 + r;
                if (grow < N_TOK) {
                    float4 v = ld4(&Pf[r * PFP + c4]);
                    float* ap = attn + abase + (size_t)r * N_TOK + gj0;
                    if (gj0 + 3 < N_TOK) {
                        *reinterpret_cast<float4*>(ap) = v;
                    } else {
#pragma unroll
                        for (int e = 0; e < 4; ++e)
                            if (gj0 + e < N_TOK) ap[e] = (&v.x)[e];
                    }
                }
            }
        }
        __syncthreads();                       // B_end: staging drained, Pf free
    }
#undef STAGE_KH
#undef STAGE_KL
#undef STAGE_VT

    // ---- epilogue: O -> LDS -> bf16 hi/lo frags ----
    float* Ofull = (float*)smem;               // [128][68] = 34,816 B
#pragma unroll
    for (int reg = 0; reg < 16; ++reg) {
        int rloc = wr + (reg & 3) + 8 * (reg >> 2) + 4 * g;
        Ofull[rloc * 68 + 32 * cw + lj] = oacc[reg];
    }
    __syncthreads();
#pragma unroll
    for (int it = 0; it < 2; ++it) {
        int task = it * 512 + tid;
        int row = task >> 3, kq = task & 7;
        const float* op = Ofull + row * 68 + kq * 8;
        float4 a = ld4(op), c = ld4(op + 4);
        sh8 hi, lo; cvt8(a, c, hi, lo);
        int gm = b * 2048 + row0 + row;
        int mtile = gm >> 7, row128 = gm & 127;
        size_t off = ((size_t)(mtile * 64 + h * 8 + kq) * 128 + row128) * 8;
        *reinterpret_cast<sh8*>(Ohg + off) = hi;
        *reinterpret_cast<sh8*>(Olg + off) = lo;
    }
}

// ---------------------------------------------------------------------------
extern "C" void kernel_launch(void* const* d_in, const int* in_sizes, int n_in,
                              void* d_out, int out_size, void* d_ws, size_t ws_size,
                              hipStream_t stream)
{
    const float* x         = (const float*)d_in[0];
    const float* w_qkv     = (const float*)d_in[1];
    const float* w_qk_self = (const float*)d_in[2];
    const float* w_out     = (const float*)d_in[3];
    const float* b_out     = (const float*)d_in[4];

    float* out  = (float*)d_out;                       // [8036,512]
    float* attn = out + (size_t)MROWS * 512;           // [4,8,2009,2009]

    // ---- workspace layout ----
    float* Qf = (float*)d_ws;                          // 8036*512 f32
    float* Kf = Qf + (size_t)MROWS * 512;
    float* Vf = Kf + (size_t)MROWS * 512;
    float* p2 = Vf + (size_t)MROWS * 512;              // proj2 [8036*1024] f32
    unsigned short* Khg = (unsigned short*)p2;         // then Khg/Klg/Vtg (24MB)
    unsigned short* Klg = Khg + 4194304;
    unsigned short* Vtg = Klg + 4194304;
    float* proj2 = p2;
    float* after_p2 = p2 + (size_t)MROWS * 1024;
    unsigned short* xh  = (unsigned short*)after_p2;   // 8192*512 halfs
    unsigned short* xl  = xh + 4194304;
    unsigned short* Wqh = xl + 4194304;                // 512*1536
    unsigned short* Wql = Wqh + 786432;
    unsigned short* Wsh = Wql + 786432;                // 512*1024
    unsigned short* Wsl = Wsh + 524288;
    unsigned short* Woh = Wsl + 524288;                // 512*512
    unsigned short* Wol = Woh + 262144;
    float* rowinv = (float*)(Wol + 262144);            // 32*2048
    float* selfE  = rowinv + 65536;                    // 32*2000*10
    unsigned short* Ohg = (unsigned short*)Kf;         // overlay (Kf dead)
    unsigned short* Olg = Ohg + 4194304;

    const int smem_pv = 8192 + 8192 + 16384            // Kh, Kl, Vt dbuf
                      + RPV * PFP * 4                  // Pf32
                      + RPV * 10 * 2 + RPV * 4;        // selfS bf16 + rinv
    // = 70,656 B -> 2 blocks/CU
    hipFuncSetAttribute((const void*)attn_pv,
                        hipFuncAttributeMaxDynamicSharedMemorySize, smem_pv);

    dim3 gx(64, 4);
    convert_x<<<gx, 256, 0, stream>>>(x, xh, xl);
    convert_w<<<768, 256, 0, stream>>>(w_qkv, w_qk_self, w_out,
                                       Wqh, Wql, Wsh, Wsl, Woh, Wol);

    dim3 g1(64, 12);
    gemm_bf16<1><<<g1, 512, 0, stream>>>(xh, xl, Wqh, Wql, Qf, nullptr);

    dim3 g2(64, 8);
    gemm_bf16<0><<<g2, 512, 0, stream>>>(xh, xl, Wsh, Wsl, proj2, nullptr);

    dim3 gs(200, 32);
    selfE_k<<<gs, 256, 0, stream>>>(proj2, selfE);

    dim3 gc(NTILES, 32);
    convert_kv<<<gc, 256, 0, stream>>>(Kf, Vf, Khg, Klg, Vtg);

    attn_rowsum<<<256, 512, 0, stream>>>(Qf, Khg, selfE, rowinv);

    attn_pv<<<512, 512, smem_pv, stream>>>(Qf, Khg, Klg, Vtg, selfE, rowinv,
                                           attn, Ohg, Olg);

    dim3 g3(64, 4);
    gemm_bf16<2><<<g3, 512, 0, stream>>>(Ohg, Olg, Woh, Wol, out, b_out);
}